// Round 12
// baseline (892.012 us; speedup 1.0000x reference)
//
#include <hip/hip_runtime.h>
#include <hip/hip_bf16.h>

// ---------------- types ----------------
typedef float f4 __attribute__((ext_vector_type(4)));
typedef float f32x4 __attribute__((ext_vector_type(4)));
typedef short short8 __attribute__((ext_vector_type(8)));
typedef unsigned short u16x4 __attribute__((ext_vector_type(4)));
typedef unsigned short u16x8 __attribute__((ext_vector_type(8)));
typedef unsigned int u32x4 __attribute__((ext_vector_type(4)));
typedef unsigned int u32x8 __attribute__((ext_vector_type(8)));

// ---------------- problem constants ----------------
#define S_LEN 1024
#define BATCH 16
#define DIM   512
#define NH    8
#define HDIM  64
#define NE    16
#define DFF   2048
#define T_TOK 16384   // S*B
#define CAP   34816   // 32768 assignments + per-expert padding to BM
#define BM    128

__device__ __forceinline__ unsigned short f2bf(float f) {
  union { float f; unsigned u; } v; v.f = f;
  unsigned r = v.u + 0x7fffu + ((v.u >> 16) & 1u);  // RTNE
  return (unsigned short)(r >> 16);
}
__device__ __forceinline__ float bf2f(unsigned short h) {
  union { unsigned u; float f; } v; v.u = ((unsigned)h) << 16;
  return v.f;
}

__device__ __forceinline__ void load_lds16(const void* g, void* l) {
  __builtin_amdgcn_global_load_lds(
      (__attribute__((address_space(1))) void*)(void*)g,
      (__attribute__((address_space(3))) void*)l, 16, 0, 0);
}

// extract hi/lo bf16 planes from 8 packed u32 (hi16|lo16)
__device__ __forceinline__ short8 pack_hi8(const unsigned* val) {
  union { unsigned u[4]; short8 s; } t;
#pragma unroll
  for (int i = 0; i < 4; i++)
    t.u[i] = (val[2 * i] >> 16) | (val[2 * i + 1] & 0xFFFF0000u);
  return t.s;
}
__device__ __forceinline__ short8 pack_lo8(const unsigned* val) {
  union { unsigned u[4]; short8 s; } t;
#pragma unroll
  for (int i = 0; i < 4; i++)
    t.u[i] = (val[2 * i] & 0xFFFFu) | (val[2 * i + 1] << 16);
  return t.s;
}

// ---------------- small utility kernels ----------------
__global__ __launch_bounds__(256) void k_cvt_bf16(const float* __restrict__ in,
                                                  unsigned short* __restrict__ outb,
                                                  size_t n) {
  size_t i = ((size_t)blockIdx.x * 256 + threadIdx.x) * 4;
  size_t stride = (size_t)gridDim.x * 1024;
  for (; i < n; i += stride) {
    f4 v = *(const f4*)&in[i];
    u16x4 o;
    o[0] = f2bf(v[0]); o[1] = f2bf(v[1]); o[2] = f2bf(v[2]); o[3] = f2bf(v[3]);
    *(u16x4*)&outb[i] = o;
  }
}

// split fp32 -> bf16 hi + bf16 lo (lo = round(x - hi))
__global__ __launch_bounds__(256) void k_split_w(const float* __restrict__ in,
                                                 unsigned short* __restrict__ hi,
                                                 unsigned short* __restrict__ lo,
                                                 size_t n) {
  size_t i = ((size_t)blockIdx.x * 256 + threadIdx.x) * 4;
  size_t stride = (size_t)gridDim.x * 1024;
  for (; i < n; i += stride) {
    f4 v = *(const f4*)&in[i];
    u16x4 h, l;
#pragma unroll
    for (int j = 0; j < 4; j++) {
      unsigned short hh = f2bf(v[j]);
      h[j] = hh;
      l[j] = f2bf(v[j] - bf2f(hh));
    }
    *(u16x4*)&hi[i] = h;
    *(u16x4*)&lo[i] = l;
  }
}

__global__ __launch_bounds__(64) void k_init(int* __restrict__ counts) {
  if (threadIdx.x < NE) counts[threadIdx.x] = 0;
}

// zero only the padding rows of each expert segment
__global__ __launch_bounds__(256) void k_zero_pad(const int* __restrict__ counts,
                                                  const int* __restrict__ off_pad,
                                                  unsigned short* __restrict__ Xg) {
  const int e = blockIdx.x;
  const int start = off_pad[e] + counts[e];
  const int end = off_pad[e + 1];
  for (int row = start; row < end; row++)
    *(unsigned int*)&Xg[(size_t)row * DIM + threadIdx.x * 2] = 0u;
}

// ---------------- split-bf16 MFMA GEMM (fp32-accurate via hi/lo) ----------------
// C = (A [+A2])[M,512] * W[N,512]^T + bias.
// epi 0: n<512 -> Q*0.125 -> p0 [B,H,S,HD] packed; n>=512 -> K -> p1 packed
// epi 1: V -> p0 [B,H,HD,S] packed (LDS-bounce transposed)
// epi 2: plain fp32 row-major -> (float*)p0  (out-proj)
__global__ __launch_bounds__(256, 2) void k_gemm_split(
    const float* __restrict__ A, const float* __restrict__ A2,
    const unsigned short* __restrict__ Wh, const unsigned short* __restrict__ Wl,
    const float* __restrict__ bias, int epi,
    unsigned* __restrict__ p0, unsigned* __restrict__ p1) {
  __shared__ __align__(16) char smem[33792];   // staging 32 KB | bounce 128x66 u32
  unsigned short* AhL = (unsigned short*)smem;
  unsigned short* AlL = (unsigned short*)(smem + 8192);
  unsigned short* WhL = (unsigned short*)(smem + 16384);
  unsigned short* WlL = (unsigned short*)(smem + 24576);
  unsigned* bounce = (unsigned*)smem;
  const int tid = threadIdx.x, lane = tid & 63, wid = tid >> 6;
  const int wm = wid >> 1, wn = wid & 1;
  const int m0 = blockIdx.x * 128, n0 = blockIdx.y * 128;
  const int row = tid >> 1, half = tid & 1;
  const int xr = (row >> 1) & 3;
  f32x4 acc[4][4] = {};
  f4 ar[4];
#pragma unroll
  for (int j = 0; j < 4; j++) {
    const size_t aoff = (size_t)(m0 + row) * 512 + half * 16 + j * 4;
    ar[j] = *(const f4*)&A[aoff];
    if (A2) { f4 v2 = *(const f4*)&A2[aoff]; ar[j] += v2; }
  }
  for (int k0 = 0; k0 < 512; k0 += 32) {
    __syncthreads();
    u16x8 hi8[2], lo8[2];
#pragma unroll
    for (int j = 0; j < 16; j++) {
      const float x = ar[j >> 2][j & 3];
      const unsigned short h = f2bf(x);
      hi8[j >> 3][j & 7] = h;
      lo8[j >> 3][j & 7] = f2bf(x - bf2f(h));
    }
    const int c0 = half * 2;
    *(u16x8*)&AhL[row * 32 + (((c0 + 0) ^ xr) << 3)] = hi8[0];
    *(u16x8*)&AhL[row * 32 + (((c0 + 1) ^ xr) << 3)] = hi8[1];
    *(u16x8*)&AlL[row * 32 + (((c0 + 0) ^ xr) << 3)] = lo8[0];
    *(u16x8*)&AlL[row * 32 + (((c0 + 1) ^ xr) << 3)] = lo8[1];
#pragma unroll
    for (int i = 0; i < 2; i++) {
      const int rowW = i * 64 + wid * 16 + (lane >> 2);
      const int clog = (lane & 3) ^ ((rowW >> 1) & 3);
      const size_t woff = (size_t)(n0 + rowW) * 512 + k0 + (clog << 3);
      load_lds16(Wh + woff, &WhL[i * 2048 + wid * 512]);
      load_lds16(Wl + woff, &WlL[i * 2048 + wid * 512]);
    }
    __syncthreads();
    if (k0 + 32 < 512) {
#pragma unroll
      for (int j = 0; j < 4; j++) {
        const size_t aoff = (size_t)(m0 + row) * 512 + k0 + 32 + half * 16 + j * 4;
        ar[j] = *(const f4*)&A[aoff];
        if (A2) { f4 v2 = *(const f4*)&A2[aoff]; ar[j] += v2; }
      }
    }
    const int l15 = lane & 15, lk = lane >> 4;
    const int xa = (l15 >> 1) & 3;
    short8 avh[4], avl[4], bvh[4], bvl[4];
#pragma unroll
    for (int mi = 0; mi < 4; mi++) {
      const int mr = wm * 64 + mi * 16 + l15;
      avh[mi] = *(const short8*)&AhL[mr * 32 + ((lk ^ xa) << 3)];
      avl[mi] = *(const short8*)&AlL[mr * 32 + ((lk ^ xa) << 3)];
    }
#pragma unroll
    for (int ni = 0; ni < 4; ni++) {
      const int nr = wn * 64 + ni * 16 + l15;
      bvh[ni] = *(const short8*)&WhL[nr * 32 + ((lk ^ xa) << 3)];
      bvl[ni] = *(const short8*)&WlL[nr * 32 + ((lk ^ xa) << 3)];
    }
#pragma unroll
    for (int mi = 0; mi < 4; mi++) {
#pragma unroll
      for (int ni = 0; ni < 4; ni++) {
        acc[mi][ni] = __builtin_amdgcn_mfma_f32_16x16x32_bf16(avh[mi], bvh[ni], acc[mi][ni], 0, 0, 0);
        acc[mi][ni] = __builtin_amdgcn_mfma_f32_16x16x32_bf16(avh[mi], bvl[ni], acc[mi][ni], 0, 0, 0);
        acc[mi][ni] = __builtin_amdgcn_mfma_f32_16x16x32_bf16(avl[mi], bvh[ni], acc[mi][ni], 0, 0, 0);
      }
    }
  }
  const int l15 = lane & 15, lq = lane >> 4;
  if (epi == 2) {
    float* of = (float*)p0;
#pragma unroll
    for (int mi = 0; mi < 4; mi++) {
      const int rb = m0 + wm * 64 + mi * 16 + (lq << 2);
#pragma unroll
      for (int ni = 0; ni < 4; ni++) {
        const int n = n0 + wn * 64 + ni * 16 + l15;
        const float bn = bias[n];
#pragma unroll
        for (int r = 0; r < 4; r++)
          of[(size_t)(rb + r) * 512 + n] = acc[mi][ni][r] + bn;
      }
    }
  } else if (epi == 0) {
#pragma unroll
    for (int mi = 0; mi < 4; mi++) {
      const int rb = m0 + wm * 64 + mi * 16 + (lq << 2);
#pragma unroll
      for (int ni = 0; ni < 4; ni++) {
        const int n = n0 + wn * 64 + ni * 16 + l15;
        const float bn = bias[n];
#pragma unroll
        for (int r = 0; r < 4; r++) {
          const int m = rb + r;
          const int bidx = m & 15, ss = m >> 4;   // token = s*B + b
          float v = acc[mi][ni][r] + bn;
          unsigned* pl;
          int nn;
          if (n < 512) { v *= 0.125f; pl = p0; nn = n; }
          else { pl = p1; nn = n - 512; }
          const size_t off = ((size_t)(bidx * NH + (nn >> 6)) * S_LEN + ss) * HDIM + (nn & 63);
          const unsigned short hh = f2bf(v);
          pl[off] = ((unsigned)hh << 16) | (unsigned)f2bf(v - bf2f(hh));
        }
      }
    }
  } else {
    // V: bounce through LDS, store [B,H,HD,S] with 8-consecutive-s 32B runs
    const int s_base = m0 >> 4;   // = blockIdx.x * 8
    for (int halfn = 0; halfn < 2; halfn++) {
      __syncthreads();
      if (wn == halfn) {
#pragma unroll
        for (int mi = 0; mi < 4; mi++) {
          const int mlb = wm * 64 + mi * 16 + (lq << 2);
#pragma unroll
          for (int ni = 0; ni < 4; ni++) {
            const int n = n0 + wn * 64 + ni * 16 + l15;
            const float bn = bias[n];
            const int nc = ni * 16 + l15;
#pragma unroll
            for (int r = 0; r < 4; r++) {
              const float v = acc[mi][ni][r] + bn;
              const unsigned short hh = f2bf(v);
              bounce[(mlb + r) * 66 + nc] =
                  ((unsigned)hh << 16) | (unsigned)f2bf(v - bf2f(hh));
            }
          }
        }
      }
      __syncthreads();
#pragma unroll
      for (int i = 0; i < 4; i++) {
        const int idx = tid + 256 * i;        // 0..1023
        const int nc = idx & 63, bb = idx >> 6;
        const int ng = n0 + halfn * 64 + nc;
        const int hh_ = ng >> 6, dd = ng & 63;
        u32x8 vals;
#pragma unroll
        for (int s = 0; s < 8; s++) vals[s] = bounce[(s * 16 + bb) * 66 + nc];
        *(u32x8*)&p0[((size_t)(bb * NH + hh_) * HDIM + dd) * S_LEN + s_base] = vals;
      }
    }
  }
}

// ---------------- split-bf16 MFMA flash attention, 8 waves x 16 q-rows ----------------
// Q,K packed u32 [B,H,S,HD]; V packed u32 [B,H,HD,S]. 128 q-rows per block;
// K/V staging+unpack shared by 8 waves. Swapped QK^T -> in-register P. LDS 36,864 B.
__global__ __launch_bounds__(512, 2) void k_attn(
    const unsigned* __restrict__ Qp, const unsigned* __restrict__ Kp,
    const unsigned* __restrict__ Vp, float* __restrict__ O) {
  const int q0 = blockIdx.x * 128;
  const int bh = blockIdx.y;
  const int b = bh >> 3, h = bh & 7;
  const size_t base = (size_t)bh * (S_LEN * HDIM);
  __shared__ unsigned short KhL[64][72], KlL[64][72];   // [key][d]
  __shared__ unsigned short VhL[64][72], VlL[64][72];   // [d][key]
  const int tid = threadIdx.x, lane = tid & 63, w = tid >> 6;
  const int l15 = lane & 15, lq = lane >> 4;
  const int srcA = l15 + 16 * ((2 * lq) & 3);
  const int srcB = l15 + 16 * ((2 * lq + 1) & 3);
  const bool selHi = (lane & 32) != 0;
  // Q fragments (unpack once)
  short8 qh[2], ql[2];
  {
    const size_t qoff = base + (size_t)(q0 + 16 * w + l15) * HDIM + lq * 8;
    u32x8 qv0 = *(const u32x8*)&Qp[qoff];
    u32x8 qv1 = *(const u32x8*)&Qp[qoff + 32];
    qh[0] = pack_hi8((const unsigned*)&qv0); ql[0] = pack_lo8((const unsigned*)&qv0);
    qh[1] = pack_hi8((const unsigned*)&qv1); ql[1] = pack_lo8((const unsigned*)&qv1);
  }
  // staging: 512 threads -> 64 rows x 8 col-chunks of 8 u32
  const int sr = tid >> 3, sq8 = (tid & 7) * 8;
  u32x4 kr[2], vr[2];
  {
    const size_t ko = base + (size_t)sr * HDIM + sq8;      // K [key][d]
    const size_t vo = base + (size_t)sr * S_LEN + sq8;     // V [d][key]
    kr[0] = *(const u32x4*)&Kp[ko]; kr[1] = *(const u32x4*)&Kp[ko + 4];
    vr[0] = *(const u32x4*)&Vp[vo]; vr[1] = *(const u32x4*)&Vp[vo + 4];
  }
  float m_ = -1e30f, l_ = 0.f;          // per-lane, q-row = q0+16w+l15
  f32x4 acc[4] = {};                    // acc[n][r]: q-rel=4lq+r, d=16n+l15

  for (int kt = 0; kt < 16; kt++) {
    {
      const unsigned* ku = (const unsigned*)kr;
      const unsigned* vu = (const unsigned*)vr;
      *(short8*)&KhL[sr][sq8] = pack_hi8(ku);
      *(short8*)&KlL[sr][sq8] = pack_lo8(ku);
      *(short8*)&VhL[sr][sq8] = pack_hi8(vu);
      *(short8*)&VlL[sr][sq8] = pack_lo8(vu);
    }
    __syncthreads();
    if (kt < 15) {   // T14 prefetch (in flight across QK+softmax+PV)
      const int s0n = (kt + 1) * 64;
      const size_t ko = base + (size_t)(s0n + sr) * HDIM + sq8;
      const size_t vo = base + (size_t)sr * S_LEN + s0n + sq8;
      kr[0] = *(const u32x4*)&Kp[ko]; kr[1] = *(const u32x4*)&Kp[ko + 4];
      vr[0] = *(const u32x4*)&Vp[vo]; vr[1] = *(const u32x4*)&Vp[vo + 4];
    }
    // ---- QK^T (swapped): sc[n][r] = S[k=16n+4lq+r][q=l15] ----
    f32x4 sc[4] = {};
#pragma unroll
    for (int c = 0; c < 2; c++) {
      short8 kfh[4], kfl[4];
#pragma unroll
      for (int n = 0; n < 4; n++) {
        kfh[n] = *(const short8*)&KhL[16 * n + l15][c * 32 + lq * 8];
        kfl[n] = *(const short8*)&KlL[16 * n + l15][c * 32 + lq * 8];
      }
#pragma unroll
      for (int n = 0; n < 4; n++) {
        sc[n] = __builtin_amdgcn_mfma_f32_16x16x32_bf16(kfh[n], qh[c], sc[n], 0, 0, 0);
        sc[n] = __builtin_amdgcn_mfma_f32_16x16x32_bf16(kfl[n], qh[c], sc[n], 0, 0, 0);
        sc[n] = __builtin_amdgcn_mfma_f32_16x16x32_bf16(kfh[n], ql[c], sc[n], 0, 0, 0);
      }
    }
    // ---- online softmax, per-lane scalar state ----
    float tm = fmaxf(fmaxf(fmaxf(sc[0][0], sc[0][1]), fmaxf(sc[0][2], sc[0][3])),
                     fmaxf(fmaxf(sc[1][0], sc[1][1]), fmaxf(sc[1][2], sc[1][3])));
    tm = fmaxf(tm, fmaxf(fmaxf(fmaxf(sc[2][0], sc[2][1]), fmaxf(sc[2][2], sc[2][3])),
                         fmaxf(fmaxf(sc[3][0], sc[3][1]), fmaxf(sc[3][2], sc[3][3]))));
    tm = fmaxf(tm, __shfl_xor(tm, 16));
    tm = fmaxf(tm, __shfl_xor(tm, 32));
    const float mn = fmaxf(m_, tm);
    const float esc = __expf(m_ - mn);
    m_ = mn;
    float rs = 0.f;
    unsigned pk[4][4];
#pragma unroll
    for (int n = 0; n < 4; n++) {
#pragma unroll
      for (int r = 0; r < 4; r++) {
        const float p = __expf(sc[n][r] - mn);
        rs += p;
        const unsigned short hh = f2bf(p);
        pk[n][r] = ((unsigned)hh << 16) | (unsigned)f2bf(p - bf2f(hh));
      }
    }
    rs += __shfl_xor(rs, 16);
    rs += __shfl_xor(rs, 32);
    l_ = l_ * esc + rs;
    float escR[4];
#pragma unroll
    for (int r = 0; r < 4; r++) escR[r] = __shfl(esc, 4 * lq + r);
#pragma unroll
    for (int n = 0; n < 4; n++) {
#pragma unroll
      for (int r = 0; r < 4; r++) acc[n][r] *= escR[r];
    }
    // ---- PV: in-register P redistribution, 3-term MFMA ----
#pragma unroll
    for (int c = 0; c < 2; c++) {
      unsigned val[8];
#pragma unroll
      for (int j = 0; j < 8; j++) {
        const int src = (j >> 2) ? srcB : srcA;
        const unsigned sA = (unsigned)__shfl((int)pk[2 * c + 0][j & 3], src);
        const unsigned sB = (unsigned)__shfl((int)pk[2 * c + 1][j & 3], src);
        val[j] = selHi ? sB : sA;
      }
      const short8 ph = pack_hi8(val);
      const short8 plo = pack_lo8(val);
      short8 vfh[4], vfl[4];
#pragma unroll
      for (int n = 0; n < 4; n++) {
        vfh[n] = *(const short8*)&VhL[16 * n + l15][c * 32 + lq * 8];
        vfl[n] = *(const short8*)&VlL[16 * n + l15][c * 32 + lq * 8];
      }
#pragma unroll
      for (int n = 0; n < 4; n++) {
        acc[n] = __builtin_amdgcn_mfma_f32_16x16x32_bf16(ph, vfh[n], acc[n], 0, 0, 0);
        acc[n] = __builtin_amdgcn_mfma_f32_16x16x32_bf16(ph, vfl[n], acc[n], 0, 0, 0);
        acc[n] = __builtin_amdgcn_mfma_f32_16x16x32_bf16(plo, vfh[n], acc[n], 0, 0, 0);
      }
    }
    __syncthreads();
  }
  const float inv = 1.f / l_;
  float invR[4];
#pragma unroll
  for (int r = 0; r < 4; r++) invR[r] = __shfl(inv, 4 * lq + r);
#pragma unroll
  for (int r = 0; r < 4; r++) {
    const int srow = q0 + 16 * w + 4 * lq + r;
    float* orow = &O[((size_t)srow * BATCH + b) * DIM + h * HDIM];
#pragma unroll
    for (int n = 0; n < 4; n++) orow[16 * n + l15] = acc[n][r] * invR[r];
  }
}

// ---------------- layernorm: x = LN(src + proj)*g + b -> out ----------------
__global__ __launch_bounds__(256) void k_ln(const float* __restrict__ src,
                                            const float* __restrict__ proj,
                                            const float* __restrict__ g,
                                            const float* __restrict__ bt,
                                            float* __restrict__ xout) {
  const int wid = threadIdx.x >> 6, lane = threadIdx.x & 63;
  const int tok = blockIdx.x * 4 + wid;
  const size_t base = (size_t)tok * DIM + lane * 8;
  f4 a0 = *(const f4*)&src[base],  a1 = *(const f4*)&src[base + 4];
  f4 p0 = *(const f4*)&proj[base], p1 = *(const f4*)&proj[base + 4];
  float x[8];
  x[0] = a0[0] + p0[0]; x[1] = a0[1] + p0[1]; x[2] = a0[2] + p0[2]; x[3] = a0[3] + p0[3];
  x[4] = a1[0] + p1[0]; x[5] = a1[1] + p1[1]; x[6] = a1[2] + p1[2]; x[7] = a1[3] + p1[3];
  float s = 0.f, sq = 0.f;
#pragma unroll
  for (int j = 0; j < 8; j++) { s += x[j]; sq = fmaf(x[j], x[j], sq); }
#pragma unroll
  for (int d = 1; d < 64; d <<= 1) { s += __shfl_xor(s, d); sq += __shfl_xor(sq, d); }
  const float mean = s * (1.f / 512.f);
  const float var = sq * (1.f / 512.f) - mean * mean;
  const float rstd = 1.f / sqrtf(var + 1e-5f);
  const int ci = lane * 8;
  f4 o0v, o1v;
#pragma unroll
  for (int j = 0; j < 4; j++) o0v[j] = (x[j] - mean) * rstd * g[ci + j] + bt[ci + j];
#pragma unroll
  for (int j = 0; j < 4; j++) o1v[j] = (x[4 + j] - mean) * rstd * g[ci + 4 + j] + bt[ci + 4 + j];
  *(f4*)&xout[base] = o0v;
  *(f4*)&xout[base + 4] = o1v;
}

// ---------------- gate: block = 16 tokens x 16 experts, 4 tiles ----------------
__global__ __launch_bounds__(256) void k_gate(const float* __restrict__ x,
                                              const float* __restrict__ gw,
                                              const float* __restrict__ gb,
                                              int* __restrict__ topi,
                                              float* __restrict__ topw,
                                              int* __restrict__ counts) {
  __shared__ float xs[16 * 520];
  __shared__ int hist[16];
  const int tid = threadIdx.x;
  const int tl = tid >> 4, e = tid & 15;
  if (tid < 16) hist[tid] = 0;
  const float gbe = gb[e];
  const float* wrow = gw + (size_t)e * DIM;
  for (int tile = 0; tile < 4; tile++) {
    const int t0 = blockIdx.x * 64 + tile * 16;
    __syncthreads();
    {
      const int r = tid >> 4, cbase = (tid & 15) * 32;
#pragma unroll
      for (int j = 0; j < 8; j++) {
        const int c = cbase + j * 4;
        const int ch = c >> 2;
        const int pc = ch ^ ((ch >> 3) & 7);
        *(f4*)&xs[r * 520 + pc * 4] = *(const f4*)&x[(size_t)(t0 + r) * DIM + c];
      }
    }
    __syncthreads();
    float d = gbe;
#pragma unroll 8
    for (int c = 0; c < DIM; c += 4) {
      const int ch = c >> 2;
      const int pc = ch ^ ((ch >> 3) & 7);
      f4 xv = *(const f4*)&xs[tl * 520 + pc * 4];
      f4 wv = *(const f4*)&wrow[c];
      d = fmaf(xv[0], wv[0], d); d = fmaf(xv[1], wv[1], d);
      d = fmaf(xv[2], wv[2], d); d = fmaf(xv[3], wv[3], d);
    }
    float v1 = d, v2 = -1e30f;
    int i1 = e, i2 = 1000;
#pragma unroll
    for (int s = 1; s < 16; s <<= 1) {
      const float ov1 = __shfl_xor(v1, s), ov2 = __shfl_xor(v2, s);
      const int oi1 = __shfl_xor(i1, s), oi2 = __shfl_xor(i2, s);
      if (ov1 > v1 || (ov1 == v1 && oi1 < i1)) {
        float nv2; int ni2;
        if (v1 > ov2 || (v1 == ov2 && i1 < oi2)) { nv2 = v1; ni2 = i1; }
        else { nv2 = ov2; ni2 = oi2; }
        v1 = ov1; i1 = oi1; v2 = nv2; i2 = ni2;
      } else if (ov1 > v2 || (ov1 == v2 && oi1 < i2)) {
        v2 = ov1; i2 = oi1;
      }
    }
    if (e == 0) {
      const int t = t0 + tl;
      const float e1 = __expf(v2 - v1);
      const float inv = 1.f / (1.f + e1);
      topi[2 * t] = i1;  topi[2 * t + 1] = i2;
      topw[2 * t] = inv; topw[2 * t + 1] = e1 * inv;
      atomicAdd(&hist[i1], 1);
      atomicAdd(&hist[i2], 1);
    }
  }
  __syncthreads();
  if (tid < 16 && hist[tid] > 0) atomicAdd(&counts[tid], hist[tid]);
}

__global__ void k_offsets(const int* __restrict__ counts,
                          int* __restrict__ off_pad, int* __restrict__ cursor) {
  if (threadIdx.x == 0) {
    int o = 0;
    off_pad[0] = 0;
    for (int e = 0; e < NE; e++) {
      cursor[e] = 0;
      o += ((counts[e] + BM - 1) / BM) * BM;
      off_pad[e + 1] = o;
    }
  }
}

// ---------------- scatter: batched slot claims; writes tokSlot inverse map ----------------
__global__ __launch_bounds__(256) void k_scatter(const float* __restrict__ x,
                                                 const int* __restrict__ topi,
                                                 const int* __restrict__ off_pad,
                                                 int* __restrict__ cursor,
                                                 int* __restrict__ tokSlot,
                                                 unsigned short* __restrict__ Xg) {
  __shared__ int lcnt[16];
  __shared__ int gbase[16];
  __shared__ int posArr[128];
  const int tid = threadIdx.x;
  const int a0 = blockIdx.x * 128;
  if (tid < 16) lcnt[tid] = 0;
  __syncthreads();
  if (tid < 128) {
    const int a = a0 + tid;
    const int e = topi[a];
    const int lrank = atomicAdd(&lcnt[e], 1);
    posArr[tid] = (e << 24) | lrank;
  }
  __syncthreads();
  if (tid < 16) {
    const int c = lcnt[tid];
    gbase[tid] = (c > 0) ? atomicAdd(&cursor[tid], c) : 0;
  }
  __syncthreads();
  if (tid < 128) {
    const int a = a0 + tid;
    const int pk = posArr[tid];
    const int e = pk >> 24, lrank = pk & 0xffffff;
    const int pos = off_pad[e] + gbase[e] + lrank;
    posArr[tid] = pos;
    tokSlot[a] = pos;
  }
  __syncthreads();
  const int w = tid >> 6, lane = tid & 63;
#pragma unroll 4
  for (int i = 0; i < 32; i++) {
    const int idx = w * 32 + i;
    const int pos = posArr[idx];
    const int tok = (a0 + idx) >> 1;
    const size_t sb = (size_t)tok * DIM + lane * 8;
    f4 v0 = *(const f4*)&x[sb], v1 = *(const f4*)&x[sb + 4];
    u16x8 hh;
    hh[0] = f2bf(v0[0]); hh[1] = f2bf(v0[1]); hh[2] = f2bf(v0[2]); hh[3] = f2bf(v0[3]);
    hh[4] = f2bf(v1[0]); hh[5] = f2bf(v1[1]); hh[6] = f2bf(v1[2]); hh[7] = f2bf(v1[3]);
    *(u16x8*)&Xg[(size_t)pos * DIM + lane * 8] = hh;
  }
}

// ---------------- grouped bf16 MFMA GEMM (MoE), T2 swizzle + T1 XCD swizzle ----------------
// epi 0: Hout = relu(acc + bias)  epi 1: Yout = acc + bias  epi 2: Yout += acc
__global__ __launch_bounds__(256) void k_gemm_bf16(
    const unsigned short* __restrict__ A, int lda,
    const unsigned short* __restrict__ Wb, size_t westride, int ldw, int wrow0,
    const float* __restrict__ bias, int bstride, int brow0,
    int K, int epi,
    unsigned short* __restrict__ Hout, int ldh,
    const int* __restrict__ off_pad) {
  int bx = blockIdx.x;
  const int nwg = gridDim.x;
  if ((nwg & 7) == 0) bx = (bx & 7) * (nwg >> 3) + (bx >> 3);
  const int m0 = bx * BM;
  if (m0 >= off_pad[NE]) return;
  int e = 0;
  while (off_pad[e + 1] <= m0) e++;
  const unsigned short* W = Wb + (size_t)e * westride;
  const int n0 = blockIdx.y * 128;
  __shared__ unsigned short Al[128 * 64];
  __shared__ unsigned short Bl[128 * 64];
  const int tid = threadIdx.x, lane = tid & 63, wid = tid >> 6;
  const int wm = wid >> 1, wn = wid & 1;
  f32x4 acc[4][4] = {};
  const int srow = wid * 32 + (lane >> 3);
  const int scol = (((lane & 7) ^ ((lane >> 3) & 7)) << 3);
  for (int k0 = 0; k0 < K; k0 += 64) {
    const unsigned short* ga = A + (size_t)(m0 + srow) * lda + k0 + scol;
    const unsigned short* gw = W + (size_t)(wrow0 + n0 + srow) * ldw + k0 + scol;
#pragma unroll
    for (int i = 0; i < 4; i++) {
      load_lds16(ga + (size_t)i * 8 * lda, &Al[(wid * 32 + i * 8) * 64]);
      load_lds16(gw + (size_t)i * 8 * ldw, &Bl[(wid * 32 + i * 8) * 64]);
    }
    __syncthreads();
#pragma unroll
    for (int kk = 0; kk < 2; kk++) {
      short8 av[4], bv[4];
      const int ckx = (kk * 4 + (lane >> 4)) ^ (lane & 7);
#pragma unroll
      for (int mi = 0; mi < 4; mi++)
        av[mi] = *(const short8*)&Al[(wm * 64 + mi * 16 + (lane & 15)) * 64 + ckx * 8];
#pragma unroll
      for (int ni = 0; ni < 4; ni++)
        bv[ni] = *(const short8*)&Bl[(wn * 64 + ni * 16 + (lane & 15)) * 64 + ckx * 8];
#pragma unroll
      for (int mi = 0; mi < 4; mi++) {
#pragma unroll
        for (int ni = 0; ni < 4; ni++)
          acc[mi][ni] = __builtin_amdgcn_mfma_f32_16x16x32_bf16(av[mi], bv[ni], acc[mi][ni], 0, 0, 0);
      }
    }
    __syncthreads();
  }
#pragma unroll
  for (int mi = 0; mi < 4; mi++) {
    const int rb = m0 + wm * 64 + mi * 16 + ((lane >> 4) << 2);
#pragma unroll
    for (int ni = 0; ni < 4; ni++) {
      const int n = n0 + wn * 64 + ni * 16 + (lane & 15);
      const float bn = (epi != 2) ? bias[(size_t)e * bstride + brow0 + n] : 0.f;
      if (epi == 0) {
#pragma unroll
        for (int r = 0; r < 4; r++) {
          float v = acc[mi][ni][r] + bn;
          v = fmaxf(v, 0.f);
          Hout[(size_t)(rb + r) * ldh + n] = f2bf(v);
        }
      } else if (epi == 1) {
#pragma unroll
        for (int r = 0; r < 4; r++)
          Hout[(size_t)(rb + r) * ldh + n] = f2bf(acc[mi][ni][r] + bn);
      } else {
#pragma unroll
        for (int r = 0; r < 4; r++) {
          const size_t yo = (size_t)(rb + r) * ldh + n;
          Hout[yo] = f2bf(acc[mi][ni][r] + bf2f(Hout[yo]));
        }
      }
    }
  }
}

// ---------------- combine: out[t] += w_a*Y[slot_a] + w_b*Y[slot_b] ----------------
__global__ __launch_bounds__(256) void k_combine(const unsigned short* __restrict__ Y,
                                                 const int* __restrict__ tokSlot,
                                                 const float* __restrict__ topw,
                                                 float* __restrict__ out) {
  const int wid = threadIdx.x >> 6, lane = threadIdx.x & 63;
  const int t = blockIdx.x * 4 + wid;
  const int pa = tokSlot[2 * t], pb = tokSlot[2 * t + 1];
  const float wa = topw[2 * t], wb = topw[2 * t + 1];
  const size_t ob = (size_t)t * DIM + lane * 8;
  u16x8 ya = *(const u16x8*)&Y[(size_t)pa * DIM + lane * 8];
  u16x8 yb = *(const u16x8*)&Y[(size_t)pb * DIM + lane * 8];
  f4 o0 = *(const f4*)&out[ob], o1 = *(const f4*)&out[ob + 4];
#pragma unroll
  for (int j = 0; j < 4; j++) o0[j] += wa * bf2f(ya[j]) + wb * bf2f(yb[j]);
#pragma unroll
  for (int j = 0; j < 4; j++) o1[j] += wa * bf2f(ya[4 + j]) + wb * bf2f(yb[4 + j]);
  *(f4*)&out[ob] = o0;
  *(f4*)&out[ob + 4] = o1;
}

// ---------------- launch ----------------
extern "C" void kernel_launch(void* const* d_in, const int* in_sizes, int n_in,
                              void* d_out, int out_size, void* d_ws, size_t ws_size,
                              hipStream_t stream) {
  const float* src       = (const float*)d_in[0];
  const float* pos       = (const float*)d_in[1];
  const float* in_proj_w = (const float*)d_in[2];
  const float* in_proj_b = (const float*)d_in[3];
  const float* out_w     = (const float*)d_in[4];
  const float* out_b     = (const float*)d_in[5];
  const float* norm1_g   = (const float*)d_in[6];
  const float* norm1_b   = (const float*)d_in[7];
  const float* gate_w    = (const float*)d_in[8];
  const float* gate_b    = (const float*)d_in[9];
  const float* w1        = (const float*)d_in[10];
  const float* b1        = (const float*)d_in[11];
  const float* w2        = (const float*)d_in[12];
  const float* b2        = (const float*)d_in[13];
  float* out = (float*)d_out;
  char* wsb = (char*)d_ws;

  // ---- lifetime-packed arena (~166.5 MiB) ----
  unsigned* Qp = (unsigned*)(wsb + 0);          // [B,H,S,HD] packed
  unsigned* Kp = (unsigned*)(wsb + 33554432);   // [B,H,S,HD] packed
  unsigned* Vp = (unsigned*)(wsb + 67108864);   // [B,H,HD,S] packed
  float* ob = (float*)(wsb + 100663296);
  float* proj = (float*)(wsb + 0);
  unsigned short* w1b = (unsigned short*)(wsb + 0);
  unsigned short* w2b = (unsigned short*)(wsb + 33554432);
  unsigned short* Xg  = (unsigned short*)(wsb + 67108864);   // 35.7 MB
  unsigned short* Hb  = (unsigned short*)(wsb + 102760448);  // CAPx512 bf16 = 35.7 MB
  unsigned short* Yb  = (unsigned short*)(wsb + 138412032);  // CAPx512 bf16 = 34.1 MB
  unsigned short* wih = (unsigned short*)(wsb + 134217728);  // dies before MoE
  unsigned short* wil = (unsigned short*)(wsb + 135790592);
  unsigned short* woh = (unsigned short*)(wsb + 137363456);
  unsigned short* wol = (unsigned short*)(wsb + 137887744);
  char* smallb = wsb + 174063616;
  int*   topi    = (int*)  (smallb + 0);
  float* topw    = (float*)(smallb + 131072);
  int*   tokSlot = (int*)  (smallb + 262144);
  int*   counts  = (int*)  (smallb + 540672);
  int*   off_pad = (int*)  (smallb + 540736);
  int*   cursor  = (int*)  (smallb + 540864);

  // 1. routing init + weight splits
  k_init<<<1, 64, 0, stream>>>(counts);
  k_split_w<<<768, 256, 0, stream>>>(in_proj_w, wih, wil, (size_t)1536 * 512);
  k_split_w<<<256, 256, 0, stream>>>(out_w, woh, wol, (size_t)512 * 512);
  // 2. Q/K projection -> packed planes [B,H,S,HD]
  k_gemm_split<<<dim3(128, 8), 256, 0, stream>>>(src, pos, wih, wil, in_proj_b, 0, Qp, Kp);
  // 3. V projection -> packed plane [B,H,HD,S]
  k_gemm_split<<<dim3(128, 4), 256, 0, stream>>>(src, nullptr, wih + (size_t)1024 * 512,
                                                 wil + (size_t)1024 * 512, in_proj_b + 1024,
                                                 1, Vp, nullptr);
  // 4. split-MFMA flash attention (8-wave, 128 q-rows/block) -> ob [S,B,D]
  k_attn<<<dim3(8, 128), 512, 0, stream>>>(Qp, Kp, Vp, ob);
  // 5. w2 -> bf16 (K plane dead)
  k_cvt_bf16<<<2048, 256, 0, stream>>>(w2, w2b, (size_t)NE * DIM * DFF);
  // 6. output projection (split MFMA) -> proj (over Qp)
  k_gemm_split<<<dim3(128, 4), 256, 0, stream>>>(ob, nullptr, woh, wol, out_b,
                                                 2, (unsigned*)proj, nullptr);
  // 7. layernorm(src + proj) -> d_out (= x)
  k_ln<<<4096, 256, 0, stream>>>(src, proj, norm1_g, norm1_b, out);
  // 8. w1 -> bf16 (proj dead)
  k_cvt_bf16<<<2048, 256, 0, stream>>>(w1, w1b, (size_t)NE * DFF * DIM);
  // 9. gate logits + top2 + counts
  k_gate<<<T_TOK / 64, 256, 0, stream>>>(out, gate_w, gate_b, topi, topw, counts);
  // 10. padded segment offsets
  k_offsets<<<1, 64, 0, stream>>>(counts, off_pad, cursor);
  // 11. zero only padding rows of Xg
  k_zero_pad<<<NE, 256, 0, stream>>>(counts, off_pad, Xg);
  // 12. scatter + gather token rows as bf16 (writes tokSlot inverse map)
  k_scatter<<<256, 256, 0, stream>>>(out, topi, off_pad, cursor, tokSlot, Xg);
  // 13. MoE, DFF quartered; GEMM2 writes per-slot Y (no atomics)
  for (int p = 0; p < 4; ++p) {
    k_gemm_bf16<<<dim3(CAP / BM, 4), 256, 0, stream>>>(
        Xg, DIM, w1b, (size_t)DFF * DIM, DIM, p * 512,
        b1, DFF, p * 512, DIM, 0, Hb, 512, off_pad);
    k_gemm_bf16<<<dim3(CAP / BM, 4), 256, 0, stream>>>(
        Hb, 512, w2b + (size_t)p * 512, (size_t)DIM * DFF, DFF, 0,
        b2, DIM, 0, 512, (p == 0 ? 1 : 2), Yb, DIM, off_pad);
  }
  // 14. combine: out[t] += w_a*Y[slot_a] + w_b*Y[slot_b]
  k_combine<<<T_TOK / 4, 256, 0, stream>>>(Yb, tokSlot, topw, out);
}

// Round 13
// 869.805 us; speedup vs baseline: 1.0255x; 1.0255x over previous
//
#include <hip/hip_runtime.h>
#include <hip/hip_bf16.h>

// ---------------- types ----------------
typedef float f4 __attribute__((ext_vector_type(4)));
typedef float f32x4 __attribute__((ext_vector_type(4)));
typedef short short8 __attribute__((ext_vector_type(8)));
typedef unsigned short u16x4 __attribute__((ext_vector_type(4)));
typedef unsigned short u16x8 __attribute__((ext_vector_type(8)));
typedef unsigned int u32x4 __attribute__((ext_vector_type(4)));
typedef unsigned int u32x8 __attribute__((ext_vector_type(8)));

// ---------------- problem constants ----------------
#define S_LEN 1024
#define BATCH 16
#define DIM   512
#define NH    8
#define HDIM  64
#define NE    16
#define DFF   2048
#define T_TOK 16384   // S*B
#define CAP   34816   // 32768 assignments + per-expert padding to BM
#define BM    128

__device__ __forceinline__ unsigned short f2bf(float f) {
  union { float f; unsigned u; } v; v.f = f;
  unsigned r = v.u + 0x7fffu + ((v.u >> 16) & 1u);  // RTNE
  return (unsigned short)(r >> 16);
}
__device__ __forceinline__ float bf2f(unsigned short h) {
  union { unsigned u; float f; } v; v.u = ((unsigned)h) << 16;
  return v.f;
}

__device__ __forceinline__ void load_lds16(const void* g, void* l) {
  __builtin_amdgcn_global_load_lds(
      (__attribute__((address_space(1))) void*)(void*)g,
      (__attribute__((address_space(3))) void*)l, 16, 0, 0);
}

// extract hi/lo bf16 planes from 8 packed u32 (hi16|lo16)
__device__ __forceinline__ short8 pack_hi8(const unsigned* val) {
  union { unsigned u[4]; short8 s; } t;
#pragma unroll
  for (int i = 0; i < 4; i++)
    t.u[i] = (val[2 * i] >> 16) | (val[2 * i + 1] & 0xFFFF0000u);
  return t.s;
}
__device__ __forceinline__ short8 pack_lo8(const unsigned* val) {
  union { unsigned u[4]; short8 s; } t;
#pragma unroll
  for (int i = 0; i < 4; i++)
    t.u[i] = (val[2 * i] & 0xFFFFu) | (val[2 * i + 1] << 16);
  return t.s;
}

// ---------------- small utility kernels ----------------
__global__ __launch_bounds__(256) void k_cvt_bf16(const float* __restrict__ in,
                                                  unsigned short* __restrict__ outb,
                                                  size_t n) {
  size_t i = ((size_t)blockIdx.x * 256 + threadIdx.x) * 4;
  size_t stride = (size_t)gridDim.x * 1024;
  for (; i < n; i += stride) {
    f4 v = *(const f4*)&in[i];
    u16x4 o;
    o[0] = f2bf(v[0]); o[1] = f2bf(v[1]); o[2] = f2bf(v[2]); o[3] = f2bf(v[3]);
    *(u16x4*)&outb[i] = o;
  }
}

// split fp32 -> bf16 hi + bf16 lo (lo = round(x - hi))
__global__ __launch_bounds__(256) void k_split_w(const float* __restrict__ in,
                                                 unsigned short* __restrict__ hi,
                                                 unsigned short* __restrict__ lo,
                                                 size_t n) {
  size_t i = ((size_t)blockIdx.x * 256 + threadIdx.x) * 4;
  size_t stride = (size_t)gridDim.x * 1024;
  for (; i < n; i += stride) {
    f4 v = *(const f4*)&in[i];
    u16x4 h, l;
#pragma unroll
    for (int j = 0; j < 4; j++) {
      unsigned short hh = f2bf(v[j]);
      h[j] = hh;
      l[j] = f2bf(v[j] - bf2f(hh));
    }
    *(u16x4*)&hi[i] = h;
    *(u16x4*)&lo[i] = l;
  }
}

__global__ __launch_bounds__(64) void k_init(int* __restrict__ counts) {
  if (threadIdx.x < NE) counts[threadIdx.x] = 0;
}

// zero only the padding rows of each expert segment
__global__ __launch_bounds__(256) void k_zero_pad(const int* __restrict__ counts,
                                                  const int* __restrict__ off_pad,
                                                  unsigned short* __restrict__ Xg) {
  const int e = blockIdx.x;
  const int start = off_pad[e] + counts[e];
  const int end = off_pad[e + 1];
  for (int row = start; row < end; row++)
    *(unsigned int*)&Xg[(size_t)row * DIM + threadIdx.x * 2] = 0u;
}

// ---------------- split-bf16 MFMA GEMM (fp32-accurate via hi/lo) ----------------
// C = (A [+A2])[M,512] * W[N,512]^T + bias.
// epi 0: n<512 -> Q*0.125 -> p0 [B,H,S,HD] packed; n>=512 -> K -> p1 packed
// epi 1: V -> p0 [B,H,HD,S] packed (LDS-bounce transposed)
// epi 2: plain fp32 row-major -> (float*)p0  (out-proj)
__global__ __launch_bounds__(256, 2) void k_gemm_split(
    const float* __restrict__ A, const float* __restrict__ A2,
    const unsigned short* __restrict__ Wh, const unsigned short* __restrict__ Wl,
    const float* __restrict__ bias, int epi,
    unsigned* __restrict__ p0, unsigned* __restrict__ p1) {
  __shared__ __align__(16) char smem[33792];   // staging 32 KB | bounce 128x66 u32
  unsigned short* AhL = (unsigned short*)smem;
  unsigned short* AlL = (unsigned short*)(smem + 8192);
  unsigned short* WhL = (unsigned short*)(smem + 16384);
  unsigned short* WlL = (unsigned short*)(smem + 24576);
  unsigned* bounce = (unsigned*)smem;
  const int tid = threadIdx.x, lane = tid & 63, wid = tid >> 6;
  const int wm = wid >> 1, wn = wid & 1;
  const int m0 = blockIdx.x * 128, n0 = blockIdx.y * 128;
  const int row = tid >> 1, half = tid & 1;
  const int xr = (row >> 1) & 3;
  f32x4 acc[4][4] = {};
  f4 ar[4];
#pragma unroll
  for (int j = 0; j < 4; j++) {
    const size_t aoff = (size_t)(m0 + row) * 512 + half * 16 + j * 4;
    ar[j] = *(const f4*)&A[aoff];
    if (A2) { f4 v2 = *(const f4*)&A2[aoff]; ar[j] += v2; }
  }
  for (int k0 = 0; k0 < 512; k0 += 32) {
    __syncthreads();
    u16x8 hi8[2], lo8[2];
#pragma unroll
    for (int j = 0; j < 16; j++) {
      const float x = ar[j >> 2][j & 3];
      const unsigned short h = f2bf(x);
      hi8[j >> 3][j & 7] = h;
      lo8[j >> 3][j & 7] = f2bf(x - bf2f(h));
    }
    const int c0 = half * 2;
    *(u16x8*)&AhL[row * 32 + (((c0 + 0) ^ xr) << 3)] = hi8[0];
    *(u16x8*)&AhL[row * 32 + (((c0 + 1) ^ xr) << 3)] = hi8[1];
    *(u16x8*)&AlL[row * 32 + (((c0 + 0) ^ xr) << 3)] = lo8[0];
    *(u16x8*)&AlL[row * 32 + (((c0 + 1) ^ xr) << 3)] = lo8[1];
#pragma unroll
    for (int i = 0; i < 2; i++) {
      const int rowW = i * 64 + wid * 16 + (lane >> 2);
      const int clog = (lane & 3) ^ ((rowW >> 1) & 3);
      const size_t woff = (size_t)(n0 + rowW) * 512 + k0 + (clog << 3);
      load_lds16(Wh + woff, &WhL[i * 2048 + wid * 512]);
      load_lds16(Wl + woff, &WlL[i * 2048 + wid * 512]);
    }
    __syncthreads();
    if (k0 + 32 < 512) {
#pragma unroll
      for (int j = 0; j < 4; j++) {
        const size_t aoff = (size_t)(m0 + row) * 512 + k0 + 32 + half * 16 + j * 4;
        ar[j] = *(const f4*)&A[aoff];
        if (A2) { f4 v2 = *(const f4*)&A2[aoff]; ar[j] += v2; }
      }
    }
    const int l15 = lane & 15, lk = lane >> 4;
    const int xa = (l15 >> 1) & 3;
    short8 avh[4], avl[4], bvh[4], bvl[4];
#pragma unroll
    for (int mi = 0; mi < 4; mi++) {
      const int mr = wm * 64 + mi * 16 + l15;
      avh[mi] = *(const short8*)&AhL[mr * 32 + ((lk ^ xa) << 3)];
      avl[mi] = *(const short8*)&AlL[mr * 32 + ((lk ^ xa) << 3)];
    }
#pragma unroll
    for (int ni = 0; ni < 4; ni++) {
      const int nr = wn * 64 + ni * 16 + l15;
      bvh[ni] = *(const short8*)&WhL[nr * 32 + ((lk ^ xa) << 3)];
      bvl[ni] = *(const short8*)&WlL[nr * 32 + ((lk ^ xa) << 3)];
    }
#pragma unroll
    for (int mi = 0; mi < 4; mi++) {
#pragma unroll
      for (int ni = 0; ni < 4; ni++) {
        acc[mi][ni] = __builtin_amdgcn_mfma_f32_16x16x32_bf16(avh[mi], bvh[ni], acc[mi][ni], 0, 0, 0);
        acc[mi][ni] = __builtin_amdgcn_mfma_f32_16x16x32_bf16(avh[mi], bvl[ni], acc[mi][ni], 0, 0, 0);
        acc[mi][ni] = __builtin_amdgcn_mfma_f32_16x16x32_bf16(avl[mi], bvh[ni], acc[mi][ni], 0, 0, 0);
      }
    }
  }
  const int l15 = lane & 15, lq = lane >> 4;
  if (epi == 2) {
    float* of = (float*)p0;
#pragma unroll
    for (int mi = 0; mi < 4; mi++) {
      const int rb = m0 + wm * 64 + mi * 16 + (lq << 2);
#pragma unroll
      for (int ni = 0; ni < 4; ni++) {
        const int n = n0 + wn * 64 + ni * 16 + l15;
        const float bn = bias[n];
#pragma unroll
        for (int r = 0; r < 4; r++)
          of[(size_t)(rb + r) * 512 + n] = acc[mi][ni][r] + bn;
      }
    }
  } else if (epi == 0) {
#pragma unroll
    for (int mi = 0; mi < 4; mi++) {
      const int rb = m0 + wm * 64 + mi * 16 + (lq << 2);
#pragma unroll
      for (int ni = 0; ni < 4; ni++) {
        const int n = n0 + wn * 64 + ni * 16 + l15;
        const float bn = bias[n];
#pragma unroll
        for (int r = 0; r < 4; r++) {
          const int m = rb + r;
          const int bidx = m & 15, ss = m >> 4;   // token = s*B + b
          float v = acc[mi][ni][r] + bn;
          unsigned* pl;
          int nn;
          if (n < 512) { v *= 0.125f; pl = p0; nn = n; }
          else { pl = p1; nn = n - 512; }
          const size_t off = ((size_t)(bidx * NH + (nn >> 6)) * S_LEN + ss) * HDIM + (nn & 63);
          const unsigned short hh = f2bf(v);
          pl[off] = ((unsigned)hh << 16) | (unsigned)f2bf(v - bf2f(hh));
        }
      }
    }
  } else {
    // V: bounce through LDS, store [B,H,HD,S] with 8-consecutive-s 32B runs
    const int s_base = m0 >> 4;   // = blockIdx.x * 8
    for (int halfn = 0; halfn < 2; halfn++) {
      __syncthreads();
      if (wn == halfn) {
#pragma unroll
        for (int mi = 0; mi < 4; mi++) {
          const int mlb = wm * 64 + mi * 16 + (lq << 2);
#pragma unroll
          for (int ni = 0; ni < 4; ni++) {
            const int n = n0 + wn * 64 + ni * 16 + l15;
            const float bn = bias[n];
            const int nc = ni * 16 + l15;
#pragma unroll
            for (int r = 0; r < 4; r++) {
              const float v = acc[mi][ni][r] + bn;
              const unsigned short hh = f2bf(v);
              bounce[(mlb + r) * 66 + nc] =
                  ((unsigned)hh << 16) | (unsigned)f2bf(v - bf2f(hh));
            }
          }
        }
      }
      __syncthreads();
#pragma unroll
      for (int i = 0; i < 4; i++) {
        const int idx = tid + 256 * i;        // 0..1023
        const int nc = idx & 63, bb = idx >> 6;
        const int ng = n0 + halfn * 64 + nc;
        const int hh_ = ng >> 6, dd = ng & 63;
        u32x8 vals;
#pragma unroll
        for (int s = 0; s < 8; s++) vals[s] = bounce[(s * 16 + bb) * 66 + nc];
        *(u32x8*)&p0[((size_t)(bb * NH + hh_) * HDIM + dd) * S_LEN + s_base] = vals;
      }
    }
  }
}

// ---------------- split-bf16 MFMA flash attention (round-11 verified version) ----------------
// Q,K packed u32 [B,H,S,HD]; V packed u32 [B,H,HD,S] (pre-transposed).
// Unpack ONCE at staging into hi/lo u16 LDS arrays; fragment reads = plain short8.
// Swapped QK^T -> in-register P. LDS = 36,864 B. 4 waves x 16 q-rows.
__global__ __launch_bounds__(256, 4) void k_attn(
    const unsigned* __restrict__ Qp, const unsigned* __restrict__ Kp,
    const unsigned* __restrict__ Vp, float* __restrict__ O) {
  const int q0 = blockIdx.x * 64;
  const int bh = blockIdx.y;
  const int b = bh >> 3, h = bh & 7;
  const size_t base = (size_t)bh * (S_LEN * HDIM);
  __shared__ unsigned short KhL[64][72], KlL[64][72];   // [key][d]
  __shared__ unsigned short VhL[64][72], VlL[64][72];   // [d][key]
  const int tid = threadIdx.x, lane = tid & 63, w = tid >> 6;
  const int l15 = lane & 15, lq = lane >> 4;
  const int srcA = l15 + 16 * ((2 * lq) & 3);
  const int srcB = l15 + 16 * ((2 * lq + 1) & 3);
  const bool selHi = (lane & 32) != 0;
  // Q fragments (unpack once)
  short8 qh[2], ql[2];
  {
    const size_t qoff = base + (size_t)(q0 + 16 * w + l15) * HDIM + lq * 8;
    u32x8 qv0 = *(const u32x8*)&Qp[qoff];
    u32x8 qv1 = *(const u32x8*)&Qp[qoff + 32];
    qh[0] = pack_hi8((const unsigned*)&qv0); ql[0] = pack_lo8((const unsigned*)&qv0);
    qh[1] = pack_hi8((const unsigned*)&qv1); ql[1] = pack_lo8((const unsigned*)&qv1);
  }
  // staging: thread -> row sr (K: key, V: d), col-quarter sq
  const int sr = tid >> 2, sq = (tid & 3) * 16;
  u32x4 kr[4], vr[4];
  {
    const size_t ko = base + (size_t)sr * HDIM + sq;       // K [key][d]
    const size_t vo = base + (size_t)sr * S_LEN + sq;      // V [d][key]
#pragma unroll
    for (int i = 0; i < 4; i++) {
      kr[i] = *(const u32x4*)&Kp[ko + 4 * i];
      vr[i] = *(const u32x4*)&Vp[vo + 4 * i];
    }
  }
  float m_ = -1e30f, l_ = 0.f;          // per-lane, q-row = q0+16w+l15
  f32x4 acc[4] = {};                    // acc[n][r]: q-rel=4lq+r, d=16n+l15

  for (int kt = 0; kt < 16; kt++) {
    // unpack staged regs -> hi/lo LDS (shared by all 4 waves)
    {
      const unsigned* ku = (const unsigned*)kr;
      const unsigned* vu = (const unsigned*)vr;
      *(short8*)&KhL[sr][sq + 0] = pack_hi8(ku);
      *(short8*)&KhL[sr][sq + 8] = pack_hi8(ku + 8);
      *(short8*)&KlL[sr][sq + 0] = pack_lo8(ku);
      *(short8*)&KlL[sr][sq + 8] = pack_lo8(ku + 8);
      *(short8*)&VhL[sr][sq + 0] = pack_hi8(vu);
      *(short8*)&VhL[sr][sq + 8] = pack_hi8(vu + 8);
      *(short8*)&VlL[sr][sq + 0] = pack_lo8(vu);
      *(short8*)&VlL[sr][sq + 8] = pack_lo8(vu + 8);
    }
    __syncthreads();
    if (kt < 15) {   // T14 prefetch (in flight across QK+softmax+PV)
      const int s0n = (kt + 1) * 64;
      const size_t ko = base + (size_t)(s0n + sr) * HDIM + sq;
      const size_t vo = base + (size_t)sr * S_LEN + s0n + sq;
#pragma unroll
      for (int i = 0; i < 4; i++) {
        kr[i] = *(const u32x4*)&Kp[ko + 4 * i];
        vr[i] = *(const u32x4*)&Vp[vo + 4 * i];
      }
    }
    // ---- QK^T (swapped): sc[n][r] = S[k=16n+4lq+r][q=l15] ----
    f32x4 sc[4] = {};
#pragma unroll
    for (int c = 0; c < 2; c++) {
      short8 kfh[4], kfl[4];
#pragma unroll
      for (int n = 0; n < 4; n++) {
        kfh[n] = *(const short8*)&KhL[16 * n + l15][c * 32 + lq * 8];
        kfl[n] = *(const short8*)&KlL[16 * n + l15][c * 32 + lq * 8];
      }
#pragma unroll
      for (int n = 0; n < 4; n++) {
        sc[n] = __builtin_amdgcn_mfma_f32_16x16x32_bf16(kfh[n], qh[c], sc[n], 0, 0, 0);
        sc[n] = __builtin_amdgcn_mfma_f32_16x16x32_bf16(kfl[n], qh[c], sc[n], 0, 0, 0);
        sc[n] = __builtin_amdgcn_mfma_f32_16x16x32_bf16(kfh[n], ql[c], sc[n], 0, 0, 0);
      }
    }
    // ---- online softmax, per-lane scalar state ----
    float tm = fmaxf(fmaxf(fmaxf(sc[0][0], sc[0][1]), fmaxf(sc[0][2], sc[0][3])),
                     fmaxf(fmaxf(sc[1][0], sc[1][1]), fmaxf(sc[1][2], sc[1][3])));
    tm = fmaxf(tm, fmaxf(fmaxf(fmaxf(sc[2][0], sc[2][1]), fmaxf(sc[2][2], sc[2][3])),
                         fmaxf(fmaxf(sc[3][0], sc[3][1]), fmaxf(sc[3][2], sc[3][3]))));
    tm = fmaxf(tm, __shfl_xor(tm, 16));
    tm = fmaxf(tm, __shfl_xor(tm, 32));
    const float mn = fmaxf(m_, tm);
    const float esc = __expf(m_ - mn);
    m_ = mn;
    float rs = 0.f;
    unsigned pk[4][4];
#pragma unroll
    for (int n = 0; n < 4; n++) {
#pragma unroll
      for (int r = 0; r < 4; r++) {
        const float p = __expf(sc[n][r] - mn);
        rs += p;
        const unsigned short hh = f2bf(p);
        pk[n][r] = ((unsigned)hh << 16) | (unsigned)f2bf(p - bf2f(hh));
      }
    }
    rs += __shfl_xor(rs, 16);
    rs += __shfl_xor(rs, 32);
    l_ = l_ * esc + rs;
    float escR[4];
#pragma unroll
    for (int r = 0; r < 4; r++) escR[r] = __shfl(esc, 4 * lq + r);
#pragma unroll
    for (int n = 0; n < 4; n++) {
#pragma unroll
      for (int r = 0; r < 4; r++) acc[n][r] *= escR[r];
    }
    // ---- PV: in-register P redistribution, 3-term MFMA ----
#pragma unroll
    for (int c = 0; c < 2; c++) {
      unsigned val[8];
#pragma unroll
      for (int j = 0; j < 8; j++) {
        const int src = (j >> 2) ? srcB : srcA;
        const unsigned sA = (unsigned)__shfl((int)pk[2 * c + 0][j & 3], src);
        const unsigned sB = (unsigned)__shfl((int)pk[2 * c + 1][j & 3], src);
        val[j] = selHi ? sB : sA;
      }
      const short8 ph = pack_hi8(val);
      const short8 plo = pack_lo8(val);
      short8 vfh[4], vfl[4];
#pragma unroll
      for (int n = 0; n < 4; n++) {
        vfh[n] = *(const short8*)&VhL[16 * n + l15][c * 32 + lq * 8];
        vfl[n] = *(const short8*)&VlL[16 * n + l15][c * 32 + lq * 8];
      }
#pragma unroll
      for (int n = 0; n < 4; n++) {
        acc[n] = __builtin_amdgcn_mfma_f32_16x16x32_bf16(ph, vfh[n], acc[n], 0, 0, 0);
        acc[n] = __builtin_amdgcn_mfma_f32_16x16x32_bf16(ph, vfl[n], acc[n], 0, 0, 0);
        acc[n] = __builtin_amdgcn_mfma_f32_16x16x32_bf16(plo, vfh[n], acc[n], 0, 0, 0);
      }
    }
    __syncthreads();
  }
  const float inv = 1.f / l_;
  float invR[4];
#pragma unroll
  for (int r = 0; r < 4; r++) invR[r] = __shfl(inv, 4 * lq + r);
#pragma unroll
  for (int r = 0; r < 4; r++) {
    const int srow = q0 + 16 * w + 4 * lq + r;
    float* orow = &O[((size_t)srow * BATCH + b) * DIM + h * HDIM];
#pragma unroll
    for (int n = 0; n < 4; n++) orow[16 * n + l15] = acc[n][r] * invR[r];
  }
}

// ---------------- layernorm: x = LN(src + proj)*g + b -> out ----------------
__global__ __launch_bounds__(256) void k_ln(const float* __restrict__ src,
                                            const float* __restrict__ proj,
                                            const float* __restrict__ g,
                                            const float* __restrict__ bt,
                                            float* __restrict__ xout) {
  const int wid = threadIdx.x >> 6, lane = threadIdx.x & 63;
  const int tok = blockIdx.x * 4 + wid;
  const size_t base = (size_t)tok * DIM + lane * 8;
  f4 a0 = *(const f4*)&src[base],  a1 = *(const f4*)&src[base + 4];
  f4 p0 = *(const f4*)&proj[base], p1 = *(const f4*)&proj[base + 4];
  float x[8];
  x[0] = a0[0] + p0[0]; x[1] = a0[1] + p0[1]; x[2] = a0[2] + p0[2]; x[3] = a0[3] + p0[3];
  x[4] = a1[0] + p1[0]; x[5] = a1[1] + p1[1]; x[6] = a1[2] + p1[2]; x[7] = a1[3] + p1[3];
  float s = 0.f, sq = 0.f;
#pragma unroll
  for (int j = 0; j < 8; j++) { s += x[j]; sq = fmaf(x[j], x[j], sq); }
#pragma unroll
  for (int d = 1; d < 64; d <<= 1) { s += __shfl_xor(s, d); sq += __shfl_xor(sq, d); }
  const float mean = s * (1.f / 512.f);
  const float var = sq * (1.f / 512.f) - mean * mean;
  const float rstd = 1.f / sqrtf(var + 1e-5f);
  const int ci = lane * 8;
  f4 o0v, o1v;
#pragma unroll
  for (int j = 0; j < 4; j++) o0v[j] = (x[j] - mean) * rstd * g[ci + j] + bt[ci + j];
#pragma unroll
  for (int j = 0; j < 4; j++) o1v[j] = (x[4 + j] - mean) * rstd * g[ci + 4 + j] + bt[ci + 4 + j];
  *(f4*)&xout[base] = o0v;
  *(f4*)&xout[base + 4] = o1v;
}

// ---------------- gate: block = 16 tokens x 16 experts, 4 tiles ----------------
__global__ __launch_bounds__(256) void k_gate(const float* __restrict__ x,
                                              const float* __restrict__ gw,
                                              const float* __restrict__ gb,
                                              int* __restrict__ topi,
                                              float* __restrict__ topw,
                                              int* __restrict__ counts) {
  __shared__ float xs[16 * 520];
  __shared__ int hist[16];
  const int tid = threadIdx.x;
  const int tl = tid >> 4, e = tid & 15;
  if (tid < 16) hist[tid] = 0;
  const float gbe = gb[e];
  const float* wrow = gw + (size_t)e * DIM;
  for (int tile = 0; tile < 4; tile++) {
    const int t0 = blockIdx.x * 64 + tile * 16;
    __syncthreads();
    {
      const int r = tid >> 4, cbase = (tid & 15) * 32;
#pragma unroll
      for (int j = 0; j < 8; j++) {
        const int c = cbase + j * 4;
        const int ch = c >> 2;
        const int pc = ch ^ ((ch >> 3) & 7);
        *(f4*)&xs[r * 520 + pc * 4] = *(const f4*)&x[(size_t)(t0 + r) * DIM + c];
      }
    }
    __syncthreads();
    float d = gbe;
#pragma unroll 8
    for (int c = 0; c < DIM; c += 4) {
      const int ch = c >> 2;
      const int pc = ch ^ ((ch >> 3) & 7);
      f4 xv = *(const f4*)&xs[tl * 520 + pc * 4];
      f4 wv = *(const f4*)&wrow[c];
      d = fmaf(xv[0], wv[0], d); d = fmaf(xv[1], wv[1], d);
      d = fmaf(xv[2], wv[2], d); d = fmaf(xv[3], wv[3], d);
    }
    float v1 = d, v2 = -1e30f;
    int i1 = e, i2 = 1000;
#pragma unroll
    for (int s = 1; s < 16; s <<= 1) {
      const float ov1 = __shfl_xor(v1, s), ov2 = __shfl_xor(v2, s);
      const int oi1 = __shfl_xor(i1, s), oi2 = __shfl_xor(i2, s);
      if (ov1 > v1 || (ov1 == v1 && oi1 < i1)) {
        float nv2; int ni2;
        if (v1 > ov2 || (v1 == ov2 && i1 < oi2)) { nv2 = v1; ni2 = i1; }
        else { nv2 = ov2; ni2 = oi2; }
        v1 = ov1; i1 = oi1; v2 = nv2; i2 = ni2;
      } else if (ov1 > v2 || (ov1 == v2 && oi1 < i2)) {
        v2 = ov1; i2 = oi1;
      }
    }
    if (e == 0) {
      const int t = t0 + tl;
      const float e1 = __expf(v2 - v1);
      const float inv = 1.f / (1.f + e1);
      topi[2 * t] = i1;  topi[2 * t + 1] = i2;
      topw[2 * t] = inv; topw[2 * t + 1] = e1 * inv;
      atomicAdd(&hist[i1], 1);
      atomicAdd(&hist[i2], 1);
    }
  }
  __syncthreads();
  if (tid < 16 && hist[tid] > 0) atomicAdd(&counts[tid], hist[tid]);
}

__global__ void k_offsets(const int* __restrict__ counts,
                          int* __restrict__ off_pad, int* __restrict__ cursor) {
  if (threadIdx.x == 0) {
    int o = 0;
    off_pad[0] = 0;
    for (int e = 0; e < NE; e++) {
      cursor[e] = 0;
      o += ((counts[e] + BM - 1) / BM) * BM;
      off_pad[e + 1] = o;
    }
  }
}

// ---------------- scatter: batched slot claims; writes tokSlot inverse map ----------------
__global__ __launch_bounds__(256) void k_scatter(const float* __restrict__ x,
                                                 const int* __restrict__ topi,
                                                 const int* __restrict__ off_pad,
                                                 int* __restrict__ cursor,
                                                 int* __restrict__ tokSlot,
                                                 unsigned short* __restrict__ Xg) {
  __shared__ int lcnt[16];
  __shared__ int gbase[16];
  __shared__ int posArr[128];
  const int tid = threadIdx.x;
  const int a0 = blockIdx.x * 128;
  if (tid < 16) lcnt[tid] = 0;
  __syncthreads();
  if (tid < 128) {
    const int a = a0 + tid;
    const int e = topi[a];
    const int lrank = atomicAdd(&lcnt[e], 1);
    posArr[tid] = (e << 24) | lrank;
  }
  __syncthreads();
  if (tid < 16) {
    const int c = lcnt[tid];
    gbase[tid] = (c > 0) ? atomicAdd(&cursor[tid], c) : 0;
  }
  __syncthreads();
  if (tid < 128) {
    const int a = a0 + tid;
    const int pk = posArr[tid];
    const int e = pk >> 24, lrank = pk & 0xffffff;
    const int pos = off_pad[e] + gbase[e] + lrank;
    posArr[tid] = pos;
    tokSlot[a] = pos;
  }
  __syncthreads();
  const int w = tid >> 6, lane = tid & 63;
#pragma unroll 4
  for (int i = 0; i < 32; i++) {
    const int idx = w * 32 + i;
    const int pos = posArr[idx];
    const int tok = (a0 + idx) >> 1;
    const size_t sb = (size_t)tok * DIM + lane * 8;
    f4 v0 = *(const f4*)&x[sb], v1 = *(const f4*)&x[sb + 4];
    u16x8 hh;
    hh[0] = f2bf(v0[0]); hh[1] = f2bf(v0[1]); hh[2] = f2bf(v0[2]); hh[3] = f2bf(v0[3]);
    hh[4] = f2bf(v1[0]); hh[5] = f2bf(v1[1]); hh[6] = f2bf(v1[2]); hh[7] = f2bf(v1[3]);
    *(u16x8*)&Xg[(size_t)pos * DIM + lane * 8] = hh;
  }
}

// ---------------- grouped bf16 MFMA GEMM (MoE), T2 swizzle + T1 XCD swizzle ----------------
// epi 0: Hout = relu(acc + bias)  epi 1: Yout = acc + bias  epi 2: Yout += acc
__global__ __launch_bounds__(256) void k_gemm_bf16(
    const unsigned short* __restrict__ A, int lda,
    const unsigned short* __restrict__ Wb, size_t westride, int ldw, int wrow0,
    const float* __restrict__ bias, int bstride, int brow0,
    int K, int epi,
    unsigned short* __restrict__ Hout, int ldh,
    const int* __restrict__ off_pad) {
  int bx = blockIdx.x;
  const int nwg = gridDim.x;
  if ((nwg & 7) == 0) bx = (bx & 7) * (nwg >> 3) + (bx >> 3);
  const int m0 = bx * BM;
  if (m0 >= off_pad[NE]) return;
  int e = 0;
  while (off_pad[e + 1] <= m0) e++;
  const unsigned short* W = Wb + (size_t)e * westride;
  const int n0 = blockIdx.y * 128;
  __shared__ unsigned short Al[128 * 64];
  __shared__ unsigned short Bl[128 * 64];
  const int tid = threadIdx.x, lane = tid & 63, wid = tid >> 6;
  const int wm = wid >> 1, wn = wid & 1;
  f32x4 acc[4][4] = {};
  const int srow = wid * 32 + (lane >> 3);
  const int scol = (((lane & 7) ^ ((lane >> 3) & 7)) << 3);
  for (int k0 = 0; k0 < K; k0 += 64) {
    const unsigned short* ga = A + (size_t)(m0 + srow) * lda + k0 + scol;
    const unsigned short* gw = W + (size_t)(wrow0 + n0 + srow) * ldw + k0 + scol;
#pragma unroll
    for (int i = 0; i < 4; i++) {
      load_lds16(ga + (size_t)i * 8 * lda, &Al[(wid * 32 + i * 8) * 64]);
      load_lds16(gw + (size_t)i * 8 * ldw, &Bl[(wid * 32 + i * 8) * 64]);
    }
    __syncthreads();
#pragma unroll
    for (int kk = 0; kk < 2; kk++) {
      short8 av[4], bv[4];
      const int ckx = (kk * 4 + (lane >> 4)) ^ (lane & 7);
#pragma unroll
      for (int mi = 0; mi < 4; mi++)
        av[mi] = *(const short8*)&Al[(wm * 64 + mi * 16 + (lane & 15)) * 64 + ckx * 8];
#pragma unroll
      for (int ni = 0; ni < 4; ni++)
        bv[ni] = *(const short8*)&Bl[(wn * 64 + ni * 16 + (lane & 15)) * 64 + ckx * 8];
#pragma unroll
      for (int mi = 0; mi < 4; mi++) {
#pragma unroll
        for (int ni = 0; ni < 4; ni++)
          acc[mi][ni] = __builtin_amdgcn_mfma_f32_16x16x32_bf16(av[mi], bv[ni], acc[mi][ni], 0, 0, 0);
      }
    }
    __syncthreads();
  }
#pragma unroll
  for (int mi = 0; mi < 4; mi++) {
    const int rb = m0 + wm * 64 + mi * 16 + ((lane >> 4) << 2);
#pragma unroll
    for (int ni = 0; ni < 4; ni++) {
      const int n = n0 + wn * 64 + ni * 16 + (lane & 15);
      const float bn = (epi != 2) ? bias[(size_t)e * bstride + brow0 + n] : 0.f;
      if (epi == 0) {
#pragma unroll
        for (int r = 0; r < 4; r++) {
          float v = acc[mi][ni][r] + bn;
          v = fmaxf(v, 0.f);
          Hout[(size_t)(rb + r) * ldh + n] = f2bf(v);
        }
      } else if (epi == 1) {
#pragma unroll
        for (int r = 0; r < 4; r++)
          Hout[(size_t)(rb + r) * ldh + n] = f2bf(acc[mi][ni][r] + bn);
      } else {
#pragma unroll
        for (int r = 0; r < 4; r++) {
          const size_t yo = (size_t)(rb + r) * ldh + n;
          Hout[yo] = f2bf(acc[mi][ni][r] + bf2f(Hout[yo]));
        }
      }
    }
  }
}

// ---------------- combine: out[t] += w_a*Y[slot_a] + w_b*Y[slot_b] ----------------
__global__ __launch_bounds__(256) void k_combine(const unsigned short* __restrict__ Y,
                                                 const int* __restrict__ tokSlot,
                                                 const float* __restrict__ topw,
                                                 float* __restrict__ out) {
  const int wid = threadIdx.x >> 6, lane = threadIdx.x & 63;
  const int t = blockIdx.x * 4 + wid;
  const int pa = tokSlot[2 * t], pb = tokSlot[2 * t + 1];
  const float wa = topw[2 * t], wb = topw[2 * t + 1];
  const size_t ob = (size_t)t * DIM + lane * 8;
  u16x8 ya = *(const u16x8*)&Y[(size_t)pa * DIM + lane * 8];
  u16x8 yb = *(const u16x8*)&Y[(size_t)pb * DIM + lane * 8];
  f4 o0 = *(const f4*)&out[ob], o1 = *(const f4*)&out[ob + 4];
#pragma unroll
  for (int j = 0; j < 4; j++) o0[j] += wa * bf2f(ya[j]) + wb * bf2f(yb[j]);
#pragma unroll
  for (int j = 0; j < 4; j++) o1[j] += wa * bf2f(ya[4 + j]) + wb * bf2f(yb[4 + j]);
  *(f4*)&out[ob] = o0;
  *(f4*)&out[ob + 4] = o1;
}

// ---------------- launch ----------------
extern "C" void kernel_launch(void* const* d_in, const int* in_sizes, int n_in,
                              void* d_out, int out_size, void* d_ws, size_t ws_size,
                              hipStream_t stream) {
  const float* src       = (const float*)d_in[0];
  const float* pos       = (const float*)d_in[1];
  const float* in_proj_w = (const float*)d_in[2];
  const float* in_proj_b = (const float*)d_in[3];
  const float* out_w     = (const float*)d_in[4];
  const float* out_b     = (const float*)d_in[5];
  const float* norm1_g   = (const float*)d_in[6];
  const float* norm1_b   = (const float*)d_in[7];
  const float* gate_w    = (const float*)d_in[8];
  const float* gate_b    = (const float*)d_in[9];
  const float* w1        = (const float*)d_in[10];
  const float* b1        = (const float*)d_in[11];
  const float* w2        = (const float*)d_in[12];
  const float* b2        = (const float*)d_in[13];
  float* out = (float*)d_out;
  char* wsb = (char*)d_ws;

  // ---- lifetime-packed arena (~166.5 MiB) ----
  unsigned* Qp = (unsigned*)(wsb + 0);          // [B,H,S,HD] packed
  unsigned* Kp = (unsigned*)(wsb + 33554432);   // [B,H,S,HD] packed
  unsigned* Vp = (unsigned*)(wsb + 67108864);   // [B,H,HD,S] packed
  float* ob = (float*)(wsb + 100663296);
  float* proj = (float*)(wsb + 0);
  unsigned short* w1b = (unsigned short*)(wsb + 0);
  unsigned short* w2b = (unsigned short*)(wsb + 33554432);
  unsigned short* Xg  = (unsigned short*)(wsb + 67108864);   // 35.7 MB
  unsigned short* Hb  = (unsigned short*)(wsb + 102760448);  // CAPx512 bf16 = 35.7 MB
  unsigned short* Yb  = (unsigned short*)(wsb + 138412032);  // CAPx512 bf16 = 34.1 MB
  unsigned short* wih = (unsigned short*)(wsb + 134217728);  // dies before MoE
  unsigned short* wil = (unsigned short*)(wsb + 135790592);
  unsigned short* woh = (unsigned short*)(wsb + 137363456);
  unsigned short* wol = (unsigned short*)(wsb + 137887744);
  char* smallb = wsb + 174063616;
  int*   topi    = (int*)  (smallb + 0);
  float* topw    = (float*)(smallb + 131072);
  int*   tokSlot = (int*)  (smallb + 262144);
  int*   counts  = (int*)  (smallb + 540672);
  int*   off_pad = (int*)  (smallb + 540736);
  int*   cursor  = (int*)  (smallb + 540864);

  // 1. routing init + weight splits
  k_init<<<1, 64, 0, stream>>>(counts);
  k_split_w<<<768, 256, 0, stream>>>(in_proj_w, wih, wil, (size_t)1536 * 512);
  k_split_w<<<256, 256, 0, stream>>>(out_w, woh, wol, (size_t)512 * 512);
  // 2. Q/K projection -> packed planes [B,H,S,HD]
  k_gemm_split<<<dim3(128, 8), 256, 0, stream>>>(src, pos, wih, wil, in_proj_b, 0, Qp, Kp);
  // 3. V projection -> packed plane [B,H,HD,S]
  k_gemm_split<<<dim3(128, 4), 256, 0, stream>>>(src, nullptr, wih + (size_t)1024 * 512,
                                                 wil + (size_t)1024 * 512, in_proj_b + 1024,
                                                 1, Vp, nullptr);
  // 4. split-MFMA flash attention (4-wave, 64 q-rows/block) -> ob [S,B,D]
  k_attn<<<dim3(16, 128), 256, 0, stream>>>(Qp, Kp, Vp, ob);
  // 5. w2 -> bf16 (K plane dead)
  k_cvt_bf16<<<2048, 256, 0, stream>>>(w2, w2b, (size_t)NE * DIM * DFF);
  // 6. output projection (split MFMA) -> proj (over Qp)
  k_gemm_split<<<dim3(128, 4), 256, 0, stream>>>(ob, nullptr, woh, wol, out_b,
                                                 2, (unsigned*)proj, nullptr);
  // 7. layernorm(src + proj) -> d_out (= x)
  k_ln<<<4096, 256, 0, stream>>>(src, proj, norm1_g, norm1_b, out);
  // 8. w1 -> bf16 (proj dead)
  k_cvt_bf16<<<2048, 256, 0, stream>>>(w1, w1b, (size_t)NE * DFF * DIM);
  // 9. gate logits + top2 + counts
  k_gate<<<T_TOK / 64, 256, 0, stream>>>(out, gate_w, gate_b, topi, topw, counts);
  // 10. padded segment offsets
  k_offsets<<<1, 64, 0, stream>>>(counts, off_pad, cursor);
  // 11. zero only padding rows of Xg
  k_zero_pad<<<NE, 256, 0, stream>>>(counts, off_pad, Xg);
  // 12. scatter + gather token rows as bf16 (writes tokSlot inverse map)
  k_scatter<<<256, 256, 0, stream>>>(out, topi, off_pad, cursor, tokSlot, Xg);
  // 13. MoE, DFF quartered; GEMM2 writes per-slot Y (no atomics)
  for (int p = 0; p < 4; ++p) {
    k_gemm_bf16<<<dim3(CAP / BM, 4), 256, 0, stream>>>(
        Xg, DIM, w1b, (size_t)DFF * DIM, DIM, p * 512,
        b1, DFF, p * 512, DIM, 0, Hb, 512, off_pad);
    k_gemm_bf16<<<dim3(CAP / BM, 4), 256, 0, stream>>>(
        Hb, 512, w2b + (size_t)p * 512, (size_t)DIM * DFF, DFF, 0,
        b2, DIM, 0, 512, (p == 0 ? 1 : 2), Yb, DIM, off_pad);
  }
  // 14. combine: out[t] += w_a*Y[slot_a] + w_b*Y[slot_b]
  k_combine<<<T_TOK / 4, 256, 0, stream>>>(Yb, tokSlot, topw, out);
}

// Round 14
// 846.357 us; speedup vs baseline: 1.0539x; 1.0277x over previous
//
#include <hip/hip_runtime.h>
#include <hip/hip_bf16.h>

// ---------------- types ----------------
typedef float f4 __attribute__((ext_vector_type(4)));
typedef float f32x4 __attribute__((ext_vector_type(4)));
typedef short short8 __attribute__((ext_vector_type(8)));
typedef unsigned short u16x4 __attribute__((ext_vector_type(4)));
typedef unsigned short u16x8 __attribute__((ext_vector_type(8)));
typedef unsigned int u32x4 __attribute__((ext_vector_type(4)));
typedef unsigned int u32x8 __attribute__((ext_vector_type(8)));

// ---------------- problem constants ----------------
#define S_LEN 1024
#define BATCH 16
#define DIM   512
#define NH    8
#define HDIM  64
#define NE    16
#define DFF   2048
#define T_TOK 16384   // S*B
#define CAP   34816   // 32768 assignments + per-expert padding to BM
#define BM    128

__device__ __forceinline__ unsigned short f2bf(float f) {
  union { float f; unsigned u; } v; v.f = f;
  unsigned r = v.u + 0x7fffu + ((v.u >> 16) & 1u);  // RTNE
  return (unsigned short)(r >> 16);
}
__device__ __forceinline__ float bf2f(unsigned short h) {
  union { unsigned u; float f; } v; v.u = ((unsigned)h) << 16;
  return v.f;
}

__device__ __forceinline__ void load_lds16(const void* g, void* l) {
  __builtin_amdgcn_global_load_lds(
      (__attribute__((address_space(1))) void*)(void*)g,
      (__attribute__((address_space(3))) void*)l, 16, 0, 0);
}

// extract hi/lo bf16 planes from 8 packed u32 (hi16|lo16)
__device__ __forceinline__ short8 pack_hi8(const unsigned* val) {
  union { unsigned u[4]; short8 s; } t;
#pragma unroll
  for (int i = 0; i < 4; i++)
    t.u[i] = (val[2 * i] >> 16) | (val[2 * i + 1] & 0xFFFF0000u);
  return t.s;
}
__device__ __forceinline__ short8 pack_lo8(const unsigned* val) {
  union { unsigned u[4]; short8 s; } t;
#pragma unroll
  for (int i = 0; i < 4; i++)
    t.u[i] = (val[2 * i] & 0xFFFFu) | (val[2 * i + 1] << 16);
  return t.s;
}

// ---------------- small utility kernels ----------------
__global__ __launch_bounds__(256) void k_cvt_bf16(const float* __restrict__ in,
                                                  unsigned short* __restrict__ outb,
                                                  size_t n) {
  size_t i = ((size_t)blockIdx.x * 256 + threadIdx.x) * 4;
  size_t stride = (size_t)gridDim.x * 1024;
  for (; i < n; i += stride) {
    f4 v = *(const f4*)&in[i];
    u16x4 o;
    o[0] = f2bf(v[0]); o[1] = f2bf(v[1]); o[2] = f2bf(v[2]); o[3] = f2bf(v[3]);
    *(u16x4*)&outb[i] = o;
  }
}

// split fp32 -> bf16 hi + bf16 lo (lo = round(x - hi))
__global__ __launch_bounds__(256) void k_split_w(const float* __restrict__ in,
                                                 unsigned short* __restrict__ hi,
                                                 unsigned short* __restrict__ lo,
                                                 size_t n) {
  size_t i = ((size_t)blockIdx.x * 256 + threadIdx.x) * 4;
  size_t stride = (size_t)gridDim.x * 1024;
  for (; i < n; i += stride) {
    f4 v = *(const f4*)&in[i];
    u16x4 h, l;
#pragma unroll
    for (int j = 0; j < 4; j++) {
      unsigned short hh = f2bf(v[j]);
      h[j] = hh;
      l[j] = f2bf(v[j] - bf2f(hh));
    }
    *(u16x4*)&hi[i] = h;
    *(u16x4*)&lo[i] = l;
  }
}

// split activations: Ah/Al = split(src+pos); Sh/Sl = split(src)
__global__ __launch_bounds__(256) void k_split_act(const float* __restrict__ src,
                                                   const float* __restrict__ pos,
                                                   unsigned short* __restrict__ Ah,
                                                   unsigned short* __restrict__ Al,
                                                   unsigned short* __restrict__ Sh,
                                                   unsigned short* __restrict__ Sl) {
  size_t i = ((size_t)blockIdx.x * 256 + threadIdx.x) * 4;
  size_t stride = (size_t)gridDim.x * 1024;
  const size_t n = (size_t)T_TOK * DIM;
  for (; i < n; i += stride) {
    f4 s = *(const f4*)&src[i];
    f4 p = *(const f4*)&pos[i];
    u16x4 ah, al, sh, sl;
#pragma unroll
    for (int j = 0; j < 4; j++) {
      const float a = s[j] + p[j];
      unsigned short hh = f2bf(a);
      ah[j] = hh; al[j] = f2bf(a - bf2f(hh));
      hh = f2bf(s[j]);
      sh[j] = hh; sl[j] = f2bf(s[j] - bf2f(hh));
    }
    *(u16x4*)&Ah[i] = ah; *(u16x4*)&Al[i] = al;
    *(u16x4*)&Sh[i] = sh; *(u16x4*)&Sl[i] = sl;
  }
}

__global__ __launch_bounds__(64) void k_init(int* __restrict__ counts) {
  if (threadIdx.x < NE) counts[threadIdx.x] = 0;
}

// zero only the padding rows of each expert segment
__global__ __launch_bounds__(256) void k_zero_pad(const int* __restrict__ counts,
                                                  const int* __restrict__ off_pad,
                                                  unsigned short* __restrict__ Xg) {
  const int e = blockIdx.x;
  const int start = off_pad[e] + counts[e];
  const int end = off_pad[e + 1];
  for (int row = start; row < end; row++)
    *(unsigned int*)&Xg[(size_t)row * DIM + threadIdx.x * 2] = 0u;
}

// ---------------- split-bf16 MFMA GEMM: all operands pre-split bf16 hi/lo ----------------
// C = A[M,512] * W[N,512]^T + bias, 3-term MFMA (hh+hl+lh). Pure async staging.
// epi 0: n<512 -> Q*0.125 -> p0 [B,H,S,HD] packed; n>=512 -> K -> p1 packed
// epi 1: V -> p0 [B,H,HD,S] packed (LDS-bounce transposed)
// epi 2: plain fp32 row-major -> (float*)p0  (out-proj)
__global__ __launch_bounds__(256, 3) void k_gemm_split(
    const unsigned short* __restrict__ Ah, const unsigned short* __restrict__ Al,
    const unsigned short* __restrict__ Wh, const unsigned short* __restrict__ Wl,
    const float* __restrict__ bias, int epi,
    unsigned* __restrict__ p0, unsigned* __restrict__ p1) {
  __shared__ __align__(16) char smem[33792];   // staging 32 KB | bounce 128x66 u32
  unsigned short* AhL = (unsigned short*)smem;
  unsigned short* AlL = (unsigned short*)(smem + 8192);
  unsigned short* WhL = (unsigned short*)(smem + 16384);
  unsigned short* WlL = (unsigned short*)(smem + 24576);
  unsigned* bounce = (unsigned*)smem;
  const int tid = threadIdx.x, lane = tid & 63, wid = tid >> 6;
  const int wm = wid >> 1, wn = wid & 1;
  const int m0 = blockIdx.x * 128, n0 = blockIdx.y * 128;
  f32x4 acc[4][4] = {};
  for (int k0 = 0; k0 < 512; k0 += 32) {
    // G21: linear LDS dest + inverse-swizzled global source, for A and W alike
#pragma unroll
    for (int i = 0; i < 2; i++) {
      const int rowT = i * 64 + wid * 16 + (lane >> 2);
      const int clog = ((lane & 3) ^ ((rowT >> 1) & 3)) << 3;
      const size_t aoff = (size_t)(m0 + rowT) * 512 + k0 + clog;
      const size_t woff = (size_t)(n0 + rowT) * 512 + k0 + clog;
      load_lds16(Ah + aoff, &AhL[i * 2048 + wid * 512]);
      load_lds16(Al + aoff, &AlL[i * 2048 + wid * 512]);
      load_lds16(Wh + woff, &WhL[i * 2048 + wid * 512]);
      load_lds16(Wl + woff, &WlL[i * 2048 + wid * 512]);
    }
    __syncthreads();
    const int l15 = lane & 15, lk = lane >> 4;
    const int xa = (l15 >> 1) & 3;
    short8 avh[4], avl[4], bvh[4], bvl[4];
#pragma unroll
    for (int mi = 0; mi < 4; mi++) {
      const int mr = wm * 64 + mi * 16 + l15;
      avh[mi] = *(const short8*)&AhL[mr * 32 + ((lk ^ xa) << 3)];
      avl[mi] = *(const short8*)&AlL[mr * 32 + ((lk ^ xa) << 3)];
    }
#pragma unroll
    for (int ni = 0; ni < 4; ni++) {
      const int nr = wn * 64 + ni * 16 + l15;
      bvh[ni] = *(const short8*)&WhL[nr * 32 + ((lk ^ xa) << 3)];
      bvl[ni] = *(const short8*)&WlL[nr * 32 + ((lk ^ xa) << 3)];
    }
#pragma unroll
    for (int mi = 0; mi < 4; mi++) {
#pragma unroll
      for (int ni = 0; ni < 4; ni++) {
        acc[mi][ni] = __builtin_amdgcn_mfma_f32_16x16x32_bf16(avh[mi], bvh[ni], acc[mi][ni], 0, 0, 0);
        acc[mi][ni] = __builtin_amdgcn_mfma_f32_16x16x32_bf16(avh[mi], bvl[ni], acc[mi][ni], 0, 0, 0);
        acc[mi][ni] = __builtin_amdgcn_mfma_f32_16x16x32_bf16(avl[mi], bvh[ni], acc[mi][ni], 0, 0, 0);
      }
    }
    __syncthreads();
  }
  const int l15 = lane & 15, lq = lane >> 4;
  if (epi == 2) {
    float* of = (float*)p0;
#pragma unroll
    for (int mi = 0; mi < 4; mi++) {
      const int rb = m0 + wm * 64 + mi * 16 + (lq << 2);
#pragma unroll
      for (int ni = 0; ni < 4; ni++) {
        const int n = n0 + wn * 64 + ni * 16 + l15;
        const float bn = bias[n];
#pragma unroll
        for (int r = 0; r < 4; r++)
          of[(size_t)(rb + r) * 512 + n] = acc[mi][ni][r] + bn;
      }
    }
  } else if (epi == 0) {
#pragma unroll
    for (int mi = 0; mi < 4; mi++) {
      const int rb = m0 + wm * 64 + mi * 16 + (lq << 2);
#pragma unroll
      for (int ni = 0; ni < 4; ni++) {
        const int n = n0 + wn * 64 + ni * 16 + l15;
        const float bn = bias[n];
#pragma unroll
        for (int r = 0; r < 4; r++) {
          const int m = rb + r;
          const int bidx = m & 15, ss = m >> 4;   // token = s*B + b
          float v = acc[mi][ni][r] + bn;
          unsigned* pl;
          int nn;
          if (n < 512) { v *= 0.125f; pl = p0; nn = n; }
          else { pl = p1; nn = n - 512; }
          const size_t off = ((size_t)(bidx * NH + (nn >> 6)) * S_LEN + ss) * HDIM + (nn & 63);
          const unsigned short hh = f2bf(v);
          pl[off] = ((unsigned)hh << 16) | (unsigned)f2bf(v - bf2f(hh));
        }
      }
    }
  } else {
    // V: bounce through LDS, store [B,H,HD,S] with 8-consecutive-s 32B runs
    const int s_base = m0 >> 4;   // = blockIdx.x * 8
    for (int halfn = 0; halfn < 2; halfn++) {
      __syncthreads();
      if (wn == halfn) {
#pragma unroll
        for (int mi = 0; mi < 4; mi++) {
          const int mlb = wm * 64 + mi * 16 + (lq << 2);
#pragma unroll
          for (int ni = 0; ni < 4; ni++) {
            const int n = n0 + wn * 64 + ni * 16 + l15;
            const float bn = bias[n];
            const int nc = ni * 16 + l15;
#pragma unroll
            for (int r = 0; r < 4; r++) {
              const float v = acc[mi][ni][r] + bn;
              const unsigned short hh = f2bf(v);
              bounce[(mlb + r) * 66 + nc] =
                  ((unsigned)hh << 16) | (unsigned)f2bf(v - bf2f(hh));
            }
          }
        }
      }
      __syncthreads();
#pragma unroll
      for (int i = 0; i < 4; i++) {
        const int idx = tid + 256 * i;        // 0..1023
        const int nc = idx & 63, bb = idx >> 6;
        const int ng = n0 + halfn * 64 + nc;
        const int hh_ = ng >> 6, dd = ng & 63;
        u32x8 vals;
#pragma unroll
        for (int s = 0; s < 8; s++) vals[s] = bounce[(s * 16 + bb) * 66 + nc];
        *(u32x8*)&p0[((size_t)(bb * NH + hh_) * HDIM + dd) * S_LEN + s_base] = vals;
      }
    }
  }
}

// ---------------- split-bf16 MFMA flash attention (verified r11 core) ----------------
// Q,K packed u32 [B,H,S,HD]; V packed u32 [B,H,HD,S]. Output as hi/lo bf16 planes.
__global__ __launch_bounds__(256, 4) void k_attn(
    const unsigned* __restrict__ Qp, const unsigned* __restrict__ Kp,
    const unsigned* __restrict__ Vp,
    unsigned short* __restrict__ Oh, unsigned short* __restrict__ Ol) {
  const int q0 = blockIdx.x * 64;
  const int bh = blockIdx.y;
  const int b = bh >> 3, h = bh & 7;
  const size_t base = (size_t)bh * (S_LEN * HDIM);
  __shared__ unsigned short KhL[64][72], KlL[64][72];   // [key][d]
  __shared__ unsigned short VhL[64][72], VlL[64][72];   // [d][key]
  const int tid = threadIdx.x, lane = tid & 63, w = tid >> 6;
  const int l15 = lane & 15, lq = lane >> 4;
  const int srcA = l15 + 16 * ((2 * lq) & 3);
  const int srcB = l15 + 16 * ((2 * lq + 1) & 3);
  const bool selHi = (lane & 32) != 0;
  short8 qh[2], ql[2];
  {
    const size_t qoff = base + (size_t)(q0 + 16 * w + l15) * HDIM + lq * 8;
    u32x8 qv0 = *(const u32x8*)&Qp[qoff];
    u32x8 qv1 = *(const u32x8*)&Qp[qoff + 32];
    qh[0] = pack_hi8((const unsigned*)&qv0); ql[0] = pack_lo8((const unsigned*)&qv0);
    qh[1] = pack_hi8((const unsigned*)&qv1); ql[1] = pack_lo8((const unsigned*)&qv1);
  }
  const int sr = tid >> 2, sq = (tid & 3) * 16;
  u32x4 kr[4], vr[4];
  {
    const size_t ko = base + (size_t)sr * HDIM + sq;       // K [key][d]
    const size_t vo = base + (size_t)sr * S_LEN + sq;      // V [d][key]
#pragma unroll
    for (int i = 0; i < 4; i++) {
      kr[i] = *(const u32x4*)&Kp[ko + 4 * i];
      vr[i] = *(const u32x4*)&Vp[vo + 4 * i];
    }
  }
  float m_ = -1e30f, l_ = 0.f;
  f32x4 acc[4] = {};

  for (int kt = 0; kt < 16; kt++) {
    {
      const unsigned* ku = (const unsigned*)kr;
      const unsigned* vu = (const unsigned*)vr;
      *(short8*)&KhL[sr][sq + 0] = pack_hi8(ku);
      *(short8*)&KhL[sr][sq + 8] = pack_hi8(ku + 8);
      *(short8*)&KlL[sr][sq + 0] = pack_lo8(ku);
      *(short8*)&KlL[sr][sq + 8] = pack_lo8(ku + 8);
      *(short8*)&VhL[sr][sq + 0] = pack_hi8(vu);
      *(short8*)&VhL[sr][sq + 8] = pack_hi8(vu + 8);
      *(short8*)&VlL[sr][sq + 0] = pack_lo8(vu);
      *(short8*)&VlL[sr][sq + 8] = pack_lo8(vu + 8);
    }
    __syncthreads();
    if (kt < 15) {
      const int s0n = (kt + 1) * 64;
      const size_t ko = base + (size_t)(s0n + sr) * HDIM + sq;
      const size_t vo = base + (size_t)sr * S_LEN + s0n + sq;
#pragma unroll
      for (int i = 0; i < 4; i++) {
        kr[i] = *(const u32x4*)&Kp[ko + 4 * i];
        vr[i] = *(const u32x4*)&Vp[vo + 4 * i];
      }
    }
    f32x4 sc[4] = {};
#pragma unroll
    for (int c = 0; c < 2; c++) {
      short8 kfh[4], kfl[4];
#pragma unroll
      for (int n = 0; n < 4; n++) {
        kfh[n] = *(const short8*)&KhL[16 * n + l15][c * 32 + lq * 8];
        kfl[n] = *(const short8*)&KlL[16 * n + l15][c * 32 + lq * 8];
      }
#pragma unroll
      for (int n = 0; n < 4; n++) {
        sc[n] = __builtin_amdgcn_mfma_f32_16x16x32_bf16(kfh[n], qh[c], sc[n], 0, 0, 0);
        sc[n] = __builtin_amdgcn_mfma_f32_16x16x32_bf16(kfl[n], qh[c], sc[n], 0, 0, 0);
        sc[n] = __builtin_amdgcn_mfma_f32_16x16x32_bf16(kfh[n], ql[c], sc[n], 0, 0, 0);
      }
    }
    float tm = fmaxf(fmaxf(fmaxf(sc[0][0], sc[0][1]), fmaxf(sc[0][2], sc[0][3])),
                     fmaxf(fmaxf(sc[1][0], sc[1][1]), fmaxf(sc[1][2], sc[1][3])));
    tm = fmaxf(tm, fmaxf(fmaxf(fmaxf(sc[2][0], sc[2][1]), fmaxf(sc[2][2], sc[2][3])),
                         fmaxf(fmaxf(sc[3][0], sc[3][1]), fmaxf(sc[3][2], sc[3][3]))));
    tm = fmaxf(tm, __shfl_xor(tm, 16));
    tm = fmaxf(tm, __shfl_xor(tm, 32));
    const float mn = fmaxf(m_, tm);
    const float esc = __expf(m_ - mn);
    m_ = mn;
    float rs = 0.f;
    unsigned pk[4][4];
#pragma unroll
    for (int n = 0; n < 4; n++) {
#pragma unroll
      for (int r = 0; r < 4; r++) {
        const float p = __expf(sc[n][r] - mn);
        rs += p;
        const unsigned short hh = f2bf(p);
        pk[n][r] = ((unsigned)hh << 16) | (unsigned)f2bf(p - bf2f(hh));
      }
    }
    rs += __shfl_xor(rs, 16);
    rs += __shfl_xor(rs, 32);
    l_ = l_ * esc + rs;
    float escR[4];
#pragma unroll
    for (int r = 0; r < 4; r++) escR[r] = __shfl(esc, 4 * lq + r);
#pragma unroll
    for (int n = 0; n < 4; n++) {
#pragma unroll
      for (int r = 0; r < 4; r++) acc[n][r] *= escR[r];
    }
#pragma unroll
    for (int c = 0; c < 2; c++) {
      unsigned val[8];
#pragma unroll
      for (int j = 0; j < 8; j++) {
        const int src = (j >> 2) ? srcB : srcA;
        const unsigned sA = (unsigned)__shfl((int)pk[2 * c + 0][j & 3], src);
        const unsigned sB = (unsigned)__shfl((int)pk[2 * c + 1][j & 3], src);
        val[j] = selHi ? sB : sA;
      }
      const short8 ph = pack_hi8(val);
      const short8 plo = pack_lo8(val);
      short8 vfh[4], vfl[4];
#pragma unroll
      for (int n = 0; n < 4; n++) {
        vfh[n] = *(const short8*)&VhL[16 * n + l15][c * 32 + lq * 8];
        vfl[n] = *(const short8*)&VlL[16 * n + l15][c * 32 + lq * 8];
      }
#pragma unroll
      for (int n = 0; n < 4; n++) {
        acc[n] = __builtin_amdgcn_mfma_f32_16x16x32_bf16(ph, vfh[n], acc[n], 0, 0, 0);
        acc[n] = __builtin_amdgcn_mfma_f32_16x16x32_bf16(ph, vfl[n], acc[n], 0, 0, 0);
        acc[n] = __builtin_amdgcn_mfma_f32_16x16x32_bf16(plo, vfh[n], acc[n], 0, 0, 0);
      }
    }
    __syncthreads();
  }
  const float inv = 1.f / l_;
  float invR[4];
#pragma unroll
  for (int r = 0; r < 4; r++) invR[r] = __shfl(inv, 4 * lq + r);
#pragma unroll
  for (int r = 0; r < 4; r++) {
    const int srow = q0 + 16 * w + 4 * lq + r;
    const size_t ro = ((size_t)srow * BATCH + b) * DIM + h * HDIM;
#pragma unroll
    for (int n = 0; n < 4; n++) {
      const float v = acc[n][r] * invR[r];
      const unsigned short hh = f2bf(v);
      Oh[ro + 16 * n + l15] = hh;
      Ol[ro + 16 * n + l15] = f2bf(v - bf2f(hh));
    }
  }
}

// ---------------- layernorm: x = LN(src + proj)*g + b -> out ----------------
__global__ __launch_bounds__(256) void k_ln(const float* __restrict__ src,
                                            const float* __restrict__ proj,
                                            const float* __restrict__ g,
                                            const float* __restrict__ bt,
                                            float* __restrict__ xout) {
  const int wid = threadIdx.x >> 6, lane = threadIdx.x & 63;
  const int tok = blockIdx.x * 4 + wid;
  const size_t base = (size_t)tok * DIM + lane * 8;
  f4 a0 = *(const f4*)&src[base],  a1 = *(const f4*)&src[base + 4];
  f4 p0 = *(const f4*)&proj[base], p1 = *(const f4*)&proj[base + 4];
  float x[8];
  x[0] = a0[0] + p0[0]; x[1] = a0[1] + p0[1]; x[2] = a0[2] + p0[2]; x[3] = a0[3] + p0[3];
  x[4] = a1[0] + p1[0]; x[5] = a1[1] + p1[1]; x[6] = a1[2] + p1[2]; x[7] = a1[3] + p1[3];
  float s = 0.f, sq = 0.f;
#pragma unroll
  for (int j = 0; j < 8; j++) { s += x[j]; sq = fmaf(x[j], x[j], sq); }
#pragma unroll
  for (int d = 1; d < 64; d <<= 1) { s += __shfl_xor(s, d); sq += __shfl_xor(sq, d); }
  const float mean = s * (1.f / 512.f);
  const float var = sq * (1.f / 512.f) - mean * mean;
  const float rstd = 1.f / sqrtf(var + 1e-5f);
  const int ci = lane * 8;
  f4 o0v, o1v;
#pragma unroll
  for (int j = 0; j < 4; j++) o0v[j] = (x[j] - mean) * rstd * g[ci + j] + bt[ci + j];
#pragma unroll
  for (int j = 0; j < 4; j++) o1v[j] = (x[4 + j] - mean) * rstd * g[ci + 4 + j] + bt[ci + 4 + j];
  *(f4*)&xout[base] = o0v;
  *(f4*)&xout[base + 4] = o1v;
}

// ---------------- gate: block = 16 tokens x 16 experts, 4 tiles ----------------
__global__ __launch_bounds__(256) void k_gate(const float* __restrict__ x,
                                              const float* __restrict__ gw,
                                              const float* __restrict__ gb,
                                              int* __restrict__ topi,
                                              float* __restrict__ topw,
                                              int* __restrict__ counts) {
  __shared__ float xs[16 * 520];
  __shared__ int hist[16];
  const int tid = threadIdx.x;
  const int tl = tid >> 4, e = tid & 15;
  if (tid < 16) hist[tid] = 0;
  const float gbe = gb[e];
  const float* wrow = gw + (size_t)e * DIM;
  for (int tile = 0; tile < 4; tile++) {
    const int t0 = blockIdx.x * 64 + tile * 16;
    __syncthreads();
    {
      const int r = tid >> 4, cbase = (tid & 15) * 32;
#pragma unroll
      for (int j = 0; j < 8; j++) {
        const int c = cbase + j * 4;
        const int ch = c >> 2;
        const int pc = ch ^ ((ch >> 3) & 7);
        *(f4*)&xs[r * 520 + pc * 4] = *(const f4*)&x[(size_t)(t0 + r) * DIM + c];
      }
    }
    __syncthreads();
    float d = gbe;
#pragma unroll 8
    for (int c = 0; c < DIM; c += 4) {
      const int ch = c >> 2;
      const int pc = ch ^ ((ch >> 3) & 7);
      f4 xv = *(const f4*)&xs[tl * 520 + pc * 4];
      f4 wv = *(const f4*)&wrow[c];
      d = fmaf(xv[0], wv[0], d); d = fmaf(xv[1], wv[1], d);
      d = fmaf(xv[2], wv[2], d); d = fmaf(xv[3], wv[3], d);
    }
    float v1 = d, v2 = -1e30f;
    int i1 = e, i2 = 1000;
#pragma unroll
    for (int s = 1; s < 16; s <<= 1) {
      const float ov1 = __shfl_xor(v1, s), ov2 = __shfl_xor(v2, s);
      const int oi1 = __shfl_xor(i1, s), oi2 = __shfl_xor(i2, s);
      if (ov1 > v1 || (ov1 == v1 && oi1 < i1)) {
        float nv2; int ni2;
        if (v1 > ov2 || (v1 == ov2 && i1 < oi2)) { nv2 = v1; ni2 = i1; }
        else { nv2 = ov2; ni2 = oi2; }
        v1 = ov1; i1 = oi1; v2 = nv2; i2 = ni2;
      } else if (ov1 > v2 || (ov1 == v2 && oi1 < i2)) {
        v2 = ov1; i2 = oi1;
      }
    }
    if (e == 0) {
      const int t = t0 + tl;
      const float e1 = __expf(v2 - v1);
      const float inv = 1.f / (1.f + e1);
      topi[2 * t] = i1;  topi[2 * t + 1] = i2;
      topw[2 * t] = inv; topw[2 * t + 1] = e1 * inv;
      atomicAdd(&hist[i1], 1);
      atomicAdd(&hist[i2], 1);
    }
  }
  __syncthreads();
  if (tid < 16 && hist[tid] > 0) atomicAdd(&counts[tid], hist[tid]);
}

__global__ void k_offsets(const int* __restrict__ counts,
                          int* __restrict__ off_pad, int* __restrict__ cursor) {
  if (threadIdx.x == 0) {
    int o = 0;
    off_pad[0] = 0;
    for (int e = 0; e < NE; e++) {
      cursor[e] = 0;
      o += ((counts[e] + BM - 1) / BM) * BM;
      off_pad[e + 1] = o;
    }
  }
}

// ---------------- scatter: batched slot claims; writes tokSlot inverse map ----------------
__global__ __launch_bounds__(256) void k_scatter(const float* __restrict__ x,
                                                 const int* __restrict__ topi,
                                                 const int* __restrict__ off_pad,
                                                 int* __restrict__ cursor,
                                                 int* __restrict__ tokSlot,
                                                 unsigned short* __restrict__ Xg) {
  __shared__ int lcnt[16];
  __shared__ int gbase[16];
  __shared__ int posArr[128];
  const int tid = threadIdx.x;
  const int a0 = blockIdx.x * 128;
  if (tid < 16) lcnt[tid] = 0;
  __syncthreads();
  if (tid < 128) {
    const int a = a0 + tid;
    const int e = topi[a];
    const int lrank = atomicAdd(&lcnt[e], 1);
    posArr[tid] = (e << 24) | lrank;
  }
  __syncthreads();
  if (tid < 16) {
    const int c = lcnt[tid];
    gbase[tid] = (c > 0) ? atomicAdd(&cursor[tid], c) : 0;
  }
  __syncthreads();
  if (tid < 128) {
    const int a = a0 + tid;
    const int pk = posArr[tid];
    const int e = pk >> 24, lrank = pk & 0xffffff;
    const int pos = off_pad[e] + gbase[e] + lrank;
    posArr[tid] = pos;
    tokSlot[a] = pos;
  }
  __syncthreads();
  const int w = tid >> 6, lane = tid & 63;
#pragma unroll 4
  for (int i = 0; i < 32; i++) {
    const int idx = w * 32 + i;
    const int pos = posArr[idx];
    const int tok = (a0 + idx) >> 1;
    const size_t sb = (size_t)tok * DIM + lane * 8;
    f4 v0 = *(const f4*)&x[sb], v1 = *(const f4*)&x[sb + 4];
    u16x8 hh;
    hh[0] = f2bf(v0[0]); hh[1] = f2bf(v0[1]); hh[2] = f2bf(v0[2]); hh[3] = f2bf(v0[3]);
    hh[4] = f2bf(v1[0]); hh[5] = f2bf(v1[1]); hh[6] = f2bf(v1[2]); hh[7] = f2bf(v1[3]);
    *(u16x8*)&Xg[(size_t)pos * DIM + lane * 8] = hh;
  }
}

// ---------------- grouped bf16 MFMA GEMM (MoE), T2 swizzle + T1 XCD swizzle ----------------
// epi 0: Hout = relu(acc + bias)  epi 1: Yout = acc + bias  epi 2: Yout += acc
__global__ __launch_bounds__(256) void k_gemm_bf16(
    const unsigned short* __restrict__ A, int lda,
    const unsigned short* __restrict__ Wb, size_t westride, int ldw, int wrow0,
    const float* __restrict__ bias, int bstride, int brow0,
    int K, int epi,
    unsigned short* __restrict__ Hout, int ldh,
    const int* __restrict__ off_pad) {
  int bx = blockIdx.x;
  const int nwg = gridDim.x;
  if ((nwg & 7) == 0) bx = (bx & 7) * (nwg >> 3) + (bx >> 3);
  const int m0 = bx * BM;
  if (m0 >= off_pad[NE]) return;
  int e = 0;
  while (off_pad[e + 1] <= m0) e++;
  const unsigned short* W = Wb + (size_t)e * westride;
  const int n0 = blockIdx.y * 128;
  __shared__ unsigned short Al[128 * 64];
  __shared__ unsigned short Bl[128 * 64];
  const int tid = threadIdx.x, lane = tid & 63, wid = tid >> 6;
  const int wm = wid >> 1, wn = wid & 1;
  f32x4 acc[4][4] = {};
  const int srow = wid * 32 + (lane >> 3);
  const int scol = (((lane & 7) ^ ((lane >> 3) & 7)) << 3);
  for (int k0 = 0; k0 < K; k0 += 64) {
    const unsigned short* ga = A + (size_t)(m0 + srow) * lda + k0 + scol;
    const unsigned short* gw = W + (size_t)(wrow0 + n0 + srow) * ldw + k0 + scol;
#pragma unroll
    for (int i = 0; i < 4; i++) {
      load_lds16(ga + (size_t)i * 8 * lda, &Al[(wid * 32 + i * 8) * 64]);
      load_lds16(gw + (size_t)i * 8 * ldw, &Bl[(wid * 32 + i * 8) * 64]);
    }
    __syncthreads();
#pragma unroll
    for (int kk = 0; kk < 2; kk++) {
      short8 av[4], bv[4];
      const int ckx = (kk * 4 + (lane >> 4)) ^ (lane & 7);
#pragma unroll
      for (int mi = 0; mi < 4; mi++)
        av[mi] = *(const short8*)&Al[(wm * 64 + mi * 16 + (lane & 15)) * 64 + ckx * 8];
#pragma unroll
      for (int ni = 0; ni < 4; ni++)
        bv[ni] = *(const short8*)&Bl[(wn * 64 + ni * 16 + (lane & 15)) * 64 + ckx * 8];
#pragma unroll
      for (int mi = 0; mi < 4; mi++) {
#pragma unroll
        for (int ni = 0; ni < 4; ni++)
          acc[mi][ni] = __builtin_amdgcn_mfma_f32_16x16x32_bf16(av[mi], bv[ni], acc[mi][ni], 0, 0, 0);
      }
    }
    __syncthreads();
  }
#pragma unroll
  for (int mi = 0; mi < 4; mi++) {
    const int rb = m0 + wm * 64 + mi * 16 + ((lane >> 4) << 2);
#pragma unroll
    for (int ni = 0; ni < 4; ni++) {
      const int n = n0 + wn * 64 + ni * 16 + (lane & 15);
      const float bn = (epi != 2) ? bias[(size_t)e * bstride + brow0 + n] : 0.f;
      if (epi == 0) {
#pragma unroll
        for (int r = 0; r < 4; r++) {
          float v = acc[mi][ni][r] + bn;
          v = fmaxf(v, 0.f);
          Hout[(size_t)(rb + r) * ldh + n] = f2bf(v);
        }
      } else if (epi == 1) {
#pragma unroll
        for (int r = 0; r < 4; r++)
          Hout[(size_t)(rb + r) * ldh + n] = f2bf(acc[mi][ni][r] + bn);
      } else {
#pragma unroll
        for (int r = 0; r < 4; r++) {
          const size_t yo = (size_t)(rb + r) * ldh + n;
          Hout[yo] = f2bf(acc[mi][ni][r] + bf2f(Hout[yo]));
        }
      }
    }
  }
}

// ---------------- combine: out[t] += w_a*Y[slot_a] + w_b*Y[slot_b] ----------------
__global__ __launch_bounds__(256) void k_combine(const unsigned short* __restrict__ Y,
                                                 const int* __restrict__ tokSlot,
                                                 const float* __restrict__ topw,
                                                 float* __restrict__ out) {
  const int wid = threadIdx.x >> 6, lane = threadIdx.x & 63;
  const int t = blockIdx.x * 4 + wid;
  const int pa = tokSlot[2 * t], pb = tokSlot[2 * t + 1];
  const float wa = topw[2 * t], wb = topw[2 * t + 1];
  const size_t ob = (size_t)t * DIM + lane * 8;
  u16x8 ya = *(const u16x8*)&Y[(size_t)pa * DIM + lane * 8];
  u16x8 yb = *(const u16x8*)&Y[(size_t)pb * DIM + lane * 8];
  f4 o0 = *(const f4*)&out[ob], o1 = *(const f4*)&out[ob + 4];
#pragma unroll
  for (int j = 0; j < 4; j++) o0[j] += wa * bf2f(ya[j]) + wb * bf2f(yb[j]);
#pragma unroll
  for (int j = 0; j < 4; j++) o1[j] += wa * bf2f(ya[4 + j]) + wb * bf2f(yb[4 + j]);
  *(f4*)&out[ob] = o0;
  *(f4*)&out[ob + 4] = o1;
}

// ---------------- launch ----------------
extern "C" void kernel_launch(void* const* d_in, const int* in_sizes, int n_in,
                              void* d_out, int out_size, void* d_ws, size_t ws_size,
                              hipStream_t stream) {
  const float* src       = (const float*)d_in[0];
  const float* pos       = (const float*)d_in[1];
  const float* in_proj_w = (const float*)d_in[2];
  const float* in_proj_b = (const float*)d_in[3];
  const float* out_w     = (const float*)d_in[4];
  const float* out_b     = (const float*)d_in[5];
  const float* norm1_g   = (const float*)d_in[6];
  const float* norm1_b   = (const float*)d_in[7];
  const float* gate_w    = (const float*)d_in[8];
  const float* gate_b    = (const float*)d_in[9];
  const float* w1        = (const float*)d_in[10];
  const float* b1        = (const float*)d_in[11];
  const float* w2        = (const float*)d_in[12];
  const float* b2        = (const float*)d_in[13];
  float* out = (float*)d_out;
  char* wsb = (char*)d_ws;

  // ---- lifetime-packed arena (~166.5 MiB) ----
  unsigned* Qp = (unsigned*)(wsb + 0);            // [B,H,S,HD] packed, 32 MB
  unsigned* Kp = (unsigned*)(wsb + 33554432);     // 32 MB
  unsigned* Vp = (unsigned*)(wsb + 67108864);     // [B,H,HD,S] packed, 32 MB
  unsigned short* Ah = (unsigned short*)(wsb + 100663296);  // split(src+pos) hi, 16 MB
  unsigned short* Al = (unsigned short*)(wsb + 117440512);  // lo, 16 MB (dead after QK)
  unsigned short* Oh = (unsigned short*)(wsb + 100663296);  // attn out hi (over Ah)
  unsigned short* Ol = (unsigned short*)(wsb + 117440512);  // attn out lo (over Al)
  unsigned short* Sh = (unsigned short*)(wsb + 134217728);  // split(src) hi, 16 MB
  unsigned short* Sl = (unsigned short*)(wsb + 150994944);  // lo, 16 MB (dead after V)
  unsigned short* wih = (unsigned short*)(wsb + 167772160); // 1.5 MB
  unsigned short* wil = (unsigned short*)(wsb + 169345024); // 1.5 MB
  unsigned short* woh = (unsigned short*)(wsb + 170917888); // 0.5 MB
  unsigned short* wol = (unsigned short*)(wsb + 171442176); // 0.5 MB
  float* proj = (float*)(wsb + 0);                           // over Qp after attn
  unsigned short* w1b = (unsigned short*)(wsb + 0);          // over proj after LN
  unsigned short* w2b = (unsigned short*)(wsb + 33554432);   // over Kp after attn
  unsigned short* Xg  = (unsigned short*)(wsb + 67108864);   // over Vp after attn
  unsigned short* Hb  = (unsigned short*)(wsb + 102760448);  // over Oh/Ol after out-proj
  unsigned short* Yb  = (unsigned short*)(wsb + 138412032);  // over Sh/Sl+w-splits (dead)
  char* smallb = wsb + 174063616;
  int*   topi    = (int*)  (smallb + 0);
  float* topw    = (float*)(smallb + 131072);
  int*   tokSlot = (int*)  (smallb + 262144);
  int*   counts  = (int*)  (smallb + 540672);
  int*   off_pad = (int*)  (smallb + 540736);
  int*   cursor  = (int*)  (smallb + 540864);

  // 1. routing init + weight/activation splits
  k_init<<<1, 64, 0, stream>>>(counts);
  k_split_w<<<768, 256, 0, stream>>>(in_proj_w, wih, wil, (size_t)1536 * 512);
  k_split_w<<<256, 256, 0, stream>>>(out_w, woh, wol, (size_t)512 * 512);
  k_split_act<<<2048, 256, 0, stream>>>(src, pos, Ah, Al, Sh, Sl);
  // 2. Q/K projection -> packed planes [B,H,S,HD]
  k_gemm_split<<<dim3(128, 8), 256, 0, stream>>>(Ah, Al, wih, wil, in_proj_b, 0, Qp, Kp);
  // 3. V projection -> packed plane [B,H,HD,S]
  k_gemm_split<<<dim3(128, 4), 256, 0, stream>>>(Sh, Sl, wih + (size_t)1024 * 512,
                                                 wil + (size_t)1024 * 512, in_proj_b + 1024,
                                                 1, Vp, nullptr);
  // 4. split-MFMA flash attention -> Oh/Ol hi/lo planes [S,B,D] (over Ah/Al)
  k_attn<<<dim3(16, 128), 256, 0, stream>>>(Qp, Kp, Vp, Oh, Ol);
  // 5. w2 -> bf16 (Kp dead)
  k_cvt_bf16<<<2048, 256, 0, stream>>>(w2, w2b, (size_t)NE * DIM * DFF);
  // 6. output projection (split MFMA, pre-split A) -> proj (over Qp)
  k_gemm_split<<<dim3(128, 4), 256, 0, stream>>>(Oh, Ol, woh, wol, out_b,
                                                 2, (unsigned*)proj, nullptr);
  // 7. layernorm(src + proj) -> d_out (= x)
  k_ln<<<4096, 256, 0, stream>>>(src, proj, norm1_g, norm1_b, out);
  // 8. w1 -> bf16 (proj dead)
  k_cvt_bf16<<<2048, 256, 0, stream>>>(w1, w1b, (size_t)NE * DFF * DIM);
  // 9. gate logits + top2 + counts
  k_gate<<<T_TOK / 64, 256, 0, stream>>>(out, gate_w, gate_b, topi, topw, counts);
  // 10. padded segment offsets
  k_offsets<<<1, 64, 0, stream>>>(counts, off_pad, cursor);
  // 11. zero only padding rows of Xg
  k_zero_pad<<<NE, 256, 0, stream>>>(counts, off_pad, Xg);
  // 12. scatter + gather token rows as bf16 (writes tokSlot inverse map)
  k_scatter<<<256, 256, 0, stream>>>(out, topi, off_pad, cursor, tokSlot, Xg);
  // 13. MoE, DFF quartered; GEMM2 writes per-slot Y (no atomics)
  for (int p = 0; p < 4; ++p) {
    k_gemm_bf16<<<dim3(CAP / BM, 4), 256, 0, stream>>>(
        Xg, DIM, w1b, (size_t)DFF * DIM, DIM, p * 512,
        b1, DFF, p * 512, DIM, 0, Hb, 512, off_pad);
    k_gemm_bf16<<<dim3(CAP / BM, 4), 256, 0, stream>>>(
        Hb, 512, w2b + (size_t)p * 512, (size_t)DIM * DFF, DFF, 0,
        b2, DIM, 0, 512, (p == 0 ? 1 : 2), Yb, DIM, off_pad);
  }
  // 14. combine: out[t] += w_a*Y[slot_a] + w_b*Y[slot_b]
  k_combine<<<T_TOK / 4, 256, 0, stream>>>(Yb, tokSlot, topw, out);
}